// Round 1
// baseline (983.725 us; speedup 1.0000x reference)
//
#include <hip/hip_runtime.h>

#define NEG_SLOPE 0.2f
#define NGRAPHS 512

__device__ __forceinline__ float wave_reduce_sum(float v) {
#pragma unroll
    for (int off = 32; off > 0; off >>= 1) v += __shfl_xor(v, off, 64);
    return v;
}

// C[M,64] = A[M,K] @ B[K,64]; fp32, tiled 64x64, BK=16
__global__ __launch_bounds__(256) void gemm64(const float* __restrict__ A,
                                              const float* __restrict__ B,
                                              float* __restrict__ C,
                                              int M, int K) {
    __shared__ float As[64][16];
    __shared__ float Bs[16][64];
    const int tid = threadIdx.x;
    const int tx = tid & 15;   // col group (4 cols)
    const int ty = tid >> 4;   // row group (4 rows)
    const int row0 = blockIdx.x * 64;
    float acc[4][4] = {};
    const int la_row = tid >> 2;        // 0..63
    const int la_col = (tid & 3) * 4;   // 0,4,8,12
    const int lb_row = tid >> 4;        // 0..15
    const int lb_col = (tid & 15) * 4;  // 0..60

    for (int k0 = 0; k0 < K; k0 += 16) {
        int ar = row0 + la_row;
        float4 av = make_float4(0.f, 0.f, 0.f, 0.f);
        if (ar < M) av = *(const float4*)(A + (size_t)ar * K + k0 + la_col);
        *(float4*)&As[la_row][la_col] = av;
        *(float4*)&Bs[lb_row][lb_col] =
            *(const float4*)(B + (size_t)(k0 + lb_row) * 64 + lb_col);
        __syncthreads();
#pragma unroll
        for (int k = 0; k < 16; ++k) {
            float a[4];
#pragma unroll
            for (int i = 0; i < 4; ++i) a[i] = As[ty * 4 + i][k];
            float4 b = *(float4*)&Bs[k][tx * 4];
#pragma unroll
            for (int i = 0; i < 4; ++i) {
                acc[i][0] += a[i] * b.x;
                acc[i][1] += a[i] * b.y;
                acc[i][2] += a[i] * b.z;
                acc[i][3] += a[i] * b.w;
            }
        }
        __syncthreads();
    }
#pragma unroll
    for (int i = 0; i < 4; ++i) {
        int row = row0 + ty * 4 + i;
        if (row < M) {
            float4 v = make_float4(acc[i][0], acc[i][1], acc[i][2], acc[i][3]);
            *(float4*)(C + (size_t)row * 64 + tx * 4) = v;
        }
    }
}

// a_s[n] = h[n,:]·att_src ; a_d[n] = h[n,:]·att_dst  (one wave per row)
__global__ __launch_bounds__(256) void att_kernel(const float* __restrict__ h,
                                                  const float* __restrict__ att_src,
                                                  const float* __restrict__ att_dst,
                                                  float* __restrict__ a_s,
                                                  float* __restrict__ a_d, int N) {
    int n = blockIdx.x * 4 + (threadIdx.x >> 6);
    int lane = threadIdx.x & 63;
    if (n >= N) return;
    float v = h[(size_t)n * 64 + lane];
    float s1 = wave_reduce_sum(v * att_src[lane]);
    float s2 = wave_reduce_sum(v * att_dst[lane]);
    if (lane == 0) { a_s[n] = s1; a_d[n] = s2; }
}

__device__ __forceinline__ void edge_sd(const int* __restrict__ ei, int E, int e,
                                        int& s, int& d) {
    if (e < E) { s = ei[e]; d = ei[E + e]; }
    else { s = d = e - E; }  // appended self-loops
}

__device__ __forceinline__ unsigned enc_f32(float f) {
    unsigned u = __float_as_uint(f);
    return (u & 0x80000000u) ? ~u : (u | 0x80000000u);
}
__device__ __forceinline__ float dec_f32(unsigned u) {
    unsigned b = (u & 0x80000000u) ? (u ^ 0x80000000u) : ~u;
    return __uint_as_float(b);
}

// pass 1: e = leakyrelu(a_s[s]+a_d[d]); segment max by dst (encoded-uint atomicMax)
__global__ __launch_bounds__(256) void edge_max_kernel(const int* __restrict__ ei,
                                                       int E, int ET,
                                                       const float* __restrict__ a_s,
                                                       const float* __restrict__ a_d,
                                                       float* __restrict__ e_val,
                                                       unsigned* __restrict__ m_enc) {
    int e = blockIdx.x * 256 + threadIdx.x;
    if (e >= ET) return;
    int s, d;
    edge_sd(ei, E, e, s, d);
    float v = a_s[s] + a_d[d];
    v = (v >= 0.f) ? v : NEG_SLOPE * v;
    e_val[e] = v;
    atomicMax(m_enc + d, enc_f32(v));
}

// pass 2: w = exp(e - m[d]); denom[d] += w
__global__ __launch_bounds__(256) void edge_expsum_kernel(const int* __restrict__ ei,
                                                          int E, int ET,
                                                          const float* __restrict__ e_val,
                                                          const unsigned* __restrict__ m_enc,
                                                          float* __restrict__ w,
                                                          float* __restrict__ denom) {
    int e = blockIdx.x * 256 + threadIdx.x;
    if (e >= ET) return;
    int s, d;
    edge_sd(ei, E, e, s, d);
    float we = __expf(e_val[e] - dec_f32(m_enc[d]));
    w[e] = we;
    atomicAdd(denom + d, we);
}

// pass 3: out[d,:] += (w/denom[d]) * h[s,:]   (one wave per edge, lane = feature)
__global__ __launch_bounds__(256) void edge_agg_kernel(const int* __restrict__ ei,
                                                       int E, int ET,
                                                       const float* __restrict__ w,
                                                       const float* __restrict__ denom,
                                                       const float* __restrict__ h,
                                                       float* __restrict__ out) {
    int e = blockIdx.x * 4 + (threadIdx.x >> 6);
    int lane = threadIdx.x & 63;
    if (e >= ET) return;
    int s, d;
    edge_sd(ei, E, e, s, d);
    float alpha = w[e] / denom[d];
    atomicAdd(out + (size_t)d * 64 + lane, alpha * h[(size_t)s * 64 + lane]);
}

__global__ __launch_bounds__(256) void bias_relu_kernel(float* __restrict__ x,
                                                        const float* __restrict__ b,
                                                        int total) {
    int i = blockIdx.x * 256 + threadIdx.x;
    if (i >= total) return;
    float v = x[i] + b[i & 63];
    x[i] = v > 0.f ? v : 0.f;
}

// mean-pool accumulate: pooled[g,:] += x[n,:]; cnt[g] += 1
__global__ __launch_bounds__(256) void pool_kernel(const float* __restrict__ x,
                                                   const int* __restrict__ batch,
                                                   float* __restrict__ pooled,
                                                   float* __restrict__ cnt, int N) {
    int n = blockIdx.x * 4 + (threadIdx.x >> 6);
    int lane = threadIdx.x & 63;
    if (n >= N) return;
    int g = batch[n];
    atomicAdd(pooled + (size_t)g * 64 + lane, x[(size_t)n * 64 + lane]);
    if (lane == 0) atomicAdd(cnt + g, 1.0f);
}

// out[g,c] = (pooled[g,:]/cnt[g]) @ Wlin[:,c] + blin[c]   (one wave per graph)
__global__ __launch_bounds__(256) void final_kernel(const float* __restrict__ pooled,
                                                    const float* __restrict__ cnt,
                                                    const float* __restrict__ Wlin,
                                                    const float* __restrict__ blin,
                                                    float* __restrict__ out) {
    int g = blockIdx.x * 4 + (threadIdx.x >> 6);
    int lane = threadIdx.x & 63;
    if (g >= NGRAPHS) return;
    float c = cnt[g];
    c = c > 1.f ? c : 1.f;
    float p = pooled[(size_t)g * 64 + lane] / c;
    float o0 = wave_reduce_sum(p * Wlin[lane * 2 + 0]);
    float o1 = wave_reduce_sum(p * Wlin[lane * 2 + 1]);
    if (lane == 0) {
        out[g * 2 + 0] = o0 + blin[0];
        out[g * 2 + 1] = o1 + blin[1];
    }
}

extern "C" void kernel_launch(void* const* d_in, const int* in_sizes, int n_in,
                              void* d_out, int out_size, void* d_ws, size_t ws_size,
                              hipStream_t stream) {
    const float* x    = (const float*)d_in[0];
    const int*   ei   = (const int*)d_in[1];    // [2,E] int32 (harness converts int64)
    const int*   batch= (const int*)d_in[2];
    const float* W1   = (const float*)d_in[3];
    const float* as1  = (const float*)d_in[4];
    const float* ad1  = (const float*)d_in[5];
    const float* b1   = (const float*)d_in[6];
    const float* W2   = (const float*)d_in[7];
    const float* as2  = (const float*)d_in[8];
    const float* ad2  = (const float*)d_in[9];
    const float* b2   = (const float*)d_in[10];
    const float* Wlin = (const float*)d_in[11];
    const float* blin = (const float*)d_in[12];
    float* out = (float*)d_out;

    const int FIN = 768;
    const int N  = in_sizes[0] / FIN;   // 50000
    const int E  = in_sizes[1] / 2;     // 800000
    const int ET = E + N;               // edges + self-loops
    const size_t N64 = (size_t)N * 64;

    // Workspace layout (floats). Total ~45.7 MB.
    float* ws     = (float*)d_ws;
    float* agg1   = ws;                         // N*64  (zeroed; becomes X1 after bias_relu)
    float* agg2   = agg1 + N64;                 // N*64  (zeroed; becomes X2)
    float* pooled = agg2 + N64;                 // 512*64 (zeroed)
    float* cnt    = pooled + (size_t)NGRAPHS*64;// 512    (zeroed)
    float* mden   = cnt + NGRAPHS;              // m_enc(N) + denom(N), zeroed per layer
    unsigned* m_enc = (unsigned*)mden;
    float* denom  = mden + N;
    float* hbuf   = denom + N;                  // N*64 (h1, then h2)
    float* a_s    = hbuf + N64;                 // N
    float* a_d    = a_s + N;                    // N
    float* e_val  = a_d + N;                    // ET
    float* wgt    = e_val + ET;                 // ET

    const int nEdgeBlk  = (ET + 255) / 256;
    const int nWaveBlkE = (ET + 3) / 4;
    const int nWaveBlkN = (N + 3) / 4;
    const int nGemmBlk  = (N + 63) / 64;

    // zero accumulators (agg1, agg2, pooled, cnt are contiguous)
    hipMemsetAsync(agg1, 0, (2 * N64 + (size_t)NGRAPHS * 64 + NGRAPHS) * sizeof(float),
                   stream);

    // ---- Layer 1 ----
    gemm64<<<nGemmBlk, 256, 0, stream>>>(x, W1, hbuf, N, FIN);
    att_kernel<<<nWaveBlkN, 256, 0, stream>>>(hbuf, as1, ad1, a_s, a_d, N);
    hipMemsetAsync(mden, 0, 2 * (size_t)N * sizeof(float), stream); // m_enc=-inf(enc), denom=0
    edge_max_kernel<<<nEdgeBlk, 256, 0, stream>>>(ei, E, ET, a_s, a_d, e_val, m_enc);
    edge_expsum_kernel<<<nEdgeBlk, 256, 0, stream>>>(ei, E, ET, e_val, m_enc, wgt, denom);
    edge_agg_kernel<<<nWaveBlkE, 256, 0, stream>>>(ei, E, ET, wgt, denom, hbuf, agg1);
    bias_relu_kernel<<<(int)((N64 + 255) / 256), 256, 0, stream>>>(agg1, b1, (int)N64);

    // ---- Layer 2 ----
    gemm64<<<nGemmBlk, 256, 0, stream>>>(agg1, W2, hbuf, N, 64);
    att_kernel<<<nWaveBlkN, 256, 0, stream>>>(hbuf, as2, ad2, a_s, a_d, N);
    hipMemsetAsync(mden, 0, 2 * (size_t)N * sizeof(float), stream);
    edge_max_kernel<<<nEdgeBlk, 256, 0, stream>>>(ei, E, ET, a_s, a_d, e_val, m_enc);
    edge_expsum_kernel<<<nEdgeBlk, 256, 0, stream>>>(ei, E, ET, e_val, m_enc, wgt, denom);
    edge_agg_kernel<<<nWaveBlkE, 256, 0, stream>>>(ei, E, ET, wgt, denom, hbuf, agg2);
    bias_relu_kernel<<<(int)((N64 + 255) / 256), 256, 0, stream>>>(agg2, b2, (int)N64);

    // ---- Pool + linear ----
    pool_kernel<<<nWaveBlkN, 256, 0, stream>>>(agg2, batch, pooled, cnt, N);
    final_kernel<<<(NGRAPHS + 3) / 4, 256, 0, stream>>>(pooled, cnt, Wlin, blin, out);
}

// Round 2
// 688.503 us; speedup vs baseline: 1.4288x; 1.4288x over previous
//
#include <hip/hip_runtime.h>

#define NEG_SLOPE 0.2f
#define NGRAPHS 512

__device__ __forceinline__ float wave_reduce_sum(float v) {
#pragma unroll
    for (int off = 32; off > 0; off >>= 1) v += __shfl_xor(v, off, 64);
    return v;
}
__device__ __forceinline__ float wave_reduce_max(float v) {
#pragma unroll
    for (int off = 32; off > 0; off >>= 1) v = fmaxf(v, __shfl_xor(v, off, 64));
    return v;
}

// C[M,64] = A[M,K] @ B[K,64]; fp32, tiled 64x64, BK=16
__global__ __launch_bounds__(256) void gemm64(const float* __restrict__ A,
                                              const float* __restrict__ B,
                                              float* __restrict__ C,
                                              int M, int K) {
    __shared__ float As[64][16];
    __shared__ float Bs[16][64];
    const int tid = threadIdx.x;
    const int tx = tid & 15;
    const int ty = tid >> 4;
    const int row0 = blockIdx.x * 64;
    float acc[4][4] = {};
    const int la_row = tid >> 2;
    const int la_col = (tid & 3) * 4;
    const int lb_row = tid >> 4;
    const int lb_col = (tid & 15) * 4;

    for (int k0 = 0; k0 < K; k0 += 16) {
        int ar = row0 + la_row;
        float4 av = make_float4(0.f, 0.f, 0.f, 0.f);
        if (ar < M) av = *(const float4*)(A + (size_t)ar * K + k0 + la_col);
        *(float4*)&As[la_row][la_col] = av;
        *(float4*)&Bs[lb_row][lb_col] =
            *(const float4*)(B + (size_t)(k0 + lb_row) * 64 + lb_col);
        __syncthreads();
#pragma unroll
        for (int k = 0; k < 16; ++k) {
            float a[4];
#pragma unroll
            for (int i = 0; i < 4; ++i) a[i] = As[ty * 4 + i][k];
            float4 b = *(float4*)&Bs[k][tx * 4];
#pragma unroll
            for (int i = 0; i < 4; ++i) {
                acc[i][0] += a[i] * b.x;
                acc[i][1] += a[i] * b.y;
                acc[i][2] += a[i] * b.z;
                acc[i][3] += a[i] * b.w;
            }
        }
        __syncthreads();
    }
#pragma unroll
    for (int i = 0; i < 4; ++i) {
        int row = row0 + ty * 4 + i;
        if (row < M) {
            float4 v = make_float4(acc[i][0], acc[i][1], acc[i][2], acc[i][3]);
            *(float4*)(C + (size_t)row * 64 + tx * 4) = v;
        }
    }
}

// a_s[n] = h[n,:]·att_src ; a_d[n] = h[n,:]·att_dst  (one wave per row)
__global__ __launch_bounds__(256) void att_kernel(const float* __restrict__ h,
                                                  const float* __restrict__ att_src,
                                                  const float* __restrict__ att_dst,
                                                  float* __restrict__ a_s,
                                                  float* __restrict__ a_d, int N) {
    int n = blockIdx.x * 4 + (threadIdx.x >> 6);
    int lane = threadIdx.x & 63;
    if (n >= N) return;
    float v = h[(size_t)n * 64 + lane];
    float s1 = wave_reduce_sum(v * att_src[lane]);
    float s2 = wave_reduce_sum(v * att_dst[lane]);
    if (lane == 0) { a_s[n] = s1; a_d[n] = s2; }
}

__device__ __forceinline__ void edge_sd(const int* __restrict__ ei, int E, int e,
                                        int& s, int& d) {
    if (e < E) { s = ei[e]; d = ei[E + e]; }
    else { s = d = e - E; }  // appended self-loops
}

// ---- CSR build ----
__global__ __launch_bounds__(256) void hist_kernel(const int* __restrict__ ei, int E,
                                                   int ET, int* __restrict__ counts) {
    int e = blockIdx.x * 256 + threadIdx.x;
    if (e >= ET) return;
    int s, d;
    edge_sd(ei, E, e, s, d);
    atomicAdd(counts + d, 1);
}

// single-block exclusive scan: row_ptr[i] = sum(counts[0..i-1]), row_ptr[N]=total
__global__ __launch_bounds__(1024) void scan_kernel(const int* __restrict__ counts,
                                                    int* __restrict__ row_ptr, int N) {
    __shared__ int wsum[16];
    __shared__ int carry_s;
    const int tid = threadIdx.x;
    const int lane = tid & 63, wid = tid >> 6;
    if (tid == 0) carry_s = 0;
    __syncthreads();
    for (int base = 0; base < N; base += 1024) {
        int i = base + tid;
        int v = (i < N) ? counts[i] : 0;
        int sv = v;
#pragma unroll
        for (int off = 1; off < 64; off <<= 1) {
            int t = __shfl_up(sv, off, 64);
            if (lane >= off) sv += t;
        }
        if (lane == 63) wsum[wid] = sv;
        __syncthreads();
        if (wid == 0 && lane < 16) {
            int wv = wsum[lane];
#pragma unroll
            for (int off = 1; off < 16; off <<= 1) {
                int t = __shfl_up(wv, off, 64);
                if (lane >= off) wv += t;
            }
            wsum[lane] = wv;
        }
        __syncthreads();
        int excl = carry_s + (wid ? wsum[wid - 1] : 0) + sv - v;
        if (i < N) row_ptr[i] = excl;
        __syncthreads();
        if (tid == 1023) carry_s = excl + v;
        __syncthreads();
    }
    if (tid == 0) row_ptr[N] = carry_s;
}

__global__ __launch_bounds__(256) void fill_kernel(const int* __restrict__ ei, int E,
                                                   int ET, int* __restrict__ next,
                                                   int* __restrict__ srcs) {
    int e = blockIdx.x * 256 + threadIdx.x;
    if (e >= ET) return;
    int s, d;
    edge_sd(ei, E, e, s, d);
    int pos = atomicAdd(next + d, 1);
    srcs[pos] = s;
}

// ---- fused edge-softmax + aggregation + bias + relu: one wave per dst node ----
__global__ __launch_bounds__(256) void gat_agg_kernel(const int* __restrict__ row_ptr,
                                                      const int* __restrict__ srcs,
                                                      const float* __restrict__ a_s,
                                                      const float* __restrict__ a_d,
                                                      const float* __restrict__ h,
                                                      const float* __restrict__ bias,
                                                      float* __restrict__ out, int N) {
    int n = blockIdx.x * 4 + (threadIdx.x >> 6);
    int lane = threadIdx.x & 63;
    if (n >= N) return;
    const int start = row_ptr[n];
    const int end = row_ptr[n + 1];
    const float adn = a_d[n];

    // pass 1: max
    float m = -1e30f;
    for (int i = start + lane; i < end; i += 64) {
        float v = a_s[srcs[i]] + adn;
        v = (v >= 0.f) ? v : NEG_SLOPE * v;
        m = fmaxf(m, v);
    }
    m = wave_reduce_max(m);

    // pass 2: sum of exp
    float l = 0.f;
    for (int i = start + lane; i < end; i += 64) {
        float v = a_s[srcs[i]] + adn;
        v = (v >= 0.f) ? v : NEG_SLOPE * v;
        l += __expf(v - m);
    }
    l = wave_reduce_sum(l);
    const float inv_den = 1.f / l;

    // pass 3: weighted gather-accumulate (chunks of 64, shfl broadcast)
    float acc = 0.f;
    for (int c = start; c < end; c += 64) {
        int cl = end - c;
        if (cl > 64) cl = 64;
        int sl = 0;
        float wl = 0.f;
        if (c + lane < end) {
            sl = srcs[c + lane];
            float v = a_s[sl] + adn;
            v = (v >= 0.f) ? v : NEG_SLOPE * v;
            wl = __expf(v - m) * inv_den;
        }
        for (int j = 0; j < cl; ++j) {
            float wj = __shfl(wl, j, 64);
            int sj = __shfl(sl, j, 64);
            acc += wj * h[(size_t)sj * 64 + lane];
        }
    }
    float o = acc + bias[lane];
    out[(size_t)n * 64 + lane] = o > 0.f ? o : 0.f;
}

// mean-pool accumulate: pooled[g,:] += x[n,:]; cnt[g] += 1
__global__ __launch_bounds__(256) void pool_kernel(const float* __restrict__ x,
                                                   const int* __restrict__ batch,
                                                   float* __restrict__ pooled,
                                                   float* __restrict__ cnt, int N) {
    int n = blockIdx.x * 4 + (threadIdx.x >> 6);
    int lane = threadIdx.x & 63;
    if (n >= N) return;
    int g = batch[n];
    atomicAdd(pooled + (size_t)g * 64 + lane, x[(size_t)n * 64 + lane]);
    if (lane == 0) atomicAdd(cnt + g, 1.0f);
}

__global__ __launch_bounds__(256) void final_kernel(const float* __restrict__ pooled,
                                                    const float* __restrict__ cnt,
                                                    const float* __restrict__ Wlin,
                                                    const float* __restrict__ blin,
                                                    float* __restrict__ out) {
    int g = blockIdx.x * 4 + (threadIdx.x >> 6);
    int lane = threadIdx.x & 63;
    if (g >= NGRAPHS) return;
    float c = cnt[g];
    c = c > 1.f ? c : 1.f;
    float p = pooled[(size_t)g * 64 + lane] / c;
    float o0 = wave_reduce_sum(p * Wlin[lane * 2 + 0]);
    float o1 = wave_reduce_sum(p * Wlin[lane * 2 + 1]);
    if (lane == 0) {
        out[g * 2 + 0] = o0 + blin[0];
        out[g * 2 + 1] = o1 + blin[1];
    }
}

extern "C" void kernel_launch(void* const* d_in, const int* in_sizes, int n_in,
                              void* d_out, int out_size, void* d_ws, size_t ws_size,
                              hipStream_t stream) {
    const float* x    = (const float*)d_in[0];
    const int*   ei   = (const int*)d_in[1];
    const int*   batch= (const int*)d_in[2];
    const float* W1   = (const float*)d_in[3];
    const float* as1  = (const float*)d_in[4];
    const float* ad1  = (const float*)d_in[5];
    const float* b1   = (const float*)d_in[6];
    const float* W2   = (const float*)d_in[7];
    const float* as2  = (const float*)d_in[8];
    const float* ad2  = (const float*)d_in[9];
    const float* b2   = (const float*)d_in[10];
    const float* Wlin = (const float*)d_in[11];
    const float* blin = (const float*)d_in[12];
    float* out = (float*)d_out;

    const int FIN = 768;
    const int N  = in_sizes[0] / FIN;   // 50000
    const int E  = in_sizes[1] / 2;     // 800000
    const int ET = E + N;
    const size_t N64 = (size_t)N * 64;

    // Workspace layout
    float* ws     = (float*)d_ws;
    float* hbuf   = ws;                          // N*64
    float* x1     = hbuf + N64;                  // N*64
    float* x2     = x1 + N64;                    // N*64
    float* a_s    = x2 + N64;                    // N
    float* a_d    = a_s + N;                     // N
    float* pooled = a_d + N;                     // 512*64
    float* cnt    = pooled + (size_t)NGRAPHS*64; // 512
    int* counts   = (int*)(cnt + NGRAPHS);       // N
    int* row_ptr  = counts + N;                  // N+1
    int* next     = row_ptr + N + 1;             // N
    int* srcs     = next + N;                    // ET

    const int nEdgeBlk  = (ET + 255) / 256;
    const int nWaveBlkN = (N + 3) / 4;
    const int nGemmBlk  = (N + 63) / 64;

    // zero: pooled, cnt, counts (contiguous)
    hipMemsetAsync(pooled, 0,
                   ((size_t)NGRAPHS * 64 + NGRAPHS + N) * sizeof(float), stream);

    // ---- CSR build (by destination), reused by both layers ----
    hist_kernel<<<nEdgeBlk, 256, 0, stream>>>(ei, E, ET, counts);
    scan_kernel<<<1, 1024, 0, stream>>>(counts, row_ptr, N);
    hipMemcpyAsync(next, row_ptr, (size_t)N * sizeof(int),
                   hipMemcpyDeviceToDevice, stream);
    fill_kernel<<<nEdgeBlk, 256, 0, stream>>>(ei, E, ET, next, srcs);

    // ---- Layer 1 ----
    gemm64<<<nGemmBlk, 256, 0, stream>>>(x, W1, hbuf, N, FIN);
    att_kernel<<<nWaveBlkN, 256, 0, stream>>>(hbuf, as1, ad1, a_s, a_d, N);
    gat_agg_kernel<<<nWaveBlkN, 256, 0, stream>>>(row_ptr, srcs, a_s, a_d, hbuf,
                                                  b1, x1, N);

    // ---- Layer 2 ----
    gemm64<<<nGemmBlk, 256, 0, stream>>>(x1, W2, hbuf, N, 64);
    att_kernel<<<nWaveBlkN, 256, 0, stream>>>(hbuf, as2, ad2, a_s, a_d, N);
    gat_agg_kernel<<<nWaveBlkN, 256, 0, stream>>>(row_ptr, srcs, a_s, a_d, hbuf,
                                                  b2, x2, N);

    // ---- Pool + linear ----
    pool_kernel<<<nWaveBlkN, 256, 0, stream>>>(x2, batch, pooled, cnt, N);
    final_kernel<<<(NGRAPHS + 3) / 4, 256, 0, stream>>>(pooled, cnt, Wlin, blin, out);
}

// Round 3
// 684.453 us; speedup vs baseline: 1.4372x; 1.0059x over previous
//
#include <hip/hip_runtime.h>

#define NEG_SLOPE 0.2f
#define NGRAPHS 512

__device__ __forceinline__ float wave_reduce_sum(float v) {
#pragma unroll
    for (int off = 32; off > 0; off >>= 1) v += __shfl_xor(v, off, 64);
    return v;
}
__device__ __forceinline__ float wave_reduce_max(float v) {
#pragma unroll
    for (int off = 32; off > 0; off >>= 1) v = fmaxf(v, __shfl_xor(v, off, 64));
    return v;
}

// C[M,64] = A[M, k_start:k_start+k_len] @ B[k_start:.., 64], split-K over blockIdx.y.
// Output for split y goes to C + y*part_stride.
// As stored k-major [16][64]: inner-loop reads are conflict-free b128 broadcasts.
__global__ __launch_bounds__(256) void gemm64s(const float* __restrict__ A,
                                               const float* __restrict__ B,
                                               float* __restrict__ C,
                                               int M, int K, int k_len,
                                               size_t part_stride) {
    __shared__ float As[16][64];   // [k][row]
    __shared__ float Bs[16][64];   // [k][col]
    const int tid = threadIdx.x;
    const int tx = tid & 15;
    const int ty = tid >> 4;
    const int row0 = blockIdx.x * 64;
    const int k_start = blockIdx.y * k_len;
    float acc[4][4] = {};
    const int la_row = tid >> 2;        // 0..63
    const int la_col = (tid & 3) * 4;   // k offset 0,4,8,12
    const int lb_row = tid >> 4;        // k 0..15
    const int lb_col = (tid & 15) * 4;  // col 0..60

    for (int k0 = k_start; k0 < k_start + k_len; k0 += 16) {
        int ar = row0 + la_row;
        float4 av = make_float4(0.f, 0.f, 0.f, 0.f);
        if (ar < M) av = *(const float4*)(A + (size_t)ar * K + k0 + la_col);
        // transpose into k-major LDS (4-way write conflict, amortized over 16 k reads)
        As[la_col + 0][la_row] = av.x;
        As[la_col + 1][la_row] = av.y;
        As[la_col + 2][la_row] = av.z;
        As[la_col + 3][la_row] = av.w;
        *(float4*)&Bs[lb_row][lb_col] =
            *(const float4*)(B + (size_t)(k0 + lb_row) * 64 + lb_col);
        __syncthreads();
#pragma unroll
        for (int k = 0; k < 16; ++k) {
            float4 a4 = *(float4*)&As[k][ty * 4];   // rows ty*4..ty*4+3
            float4 b4 = *(float4*)&Bs[k][tx * 4];   // cols tx*4..tx*4+3
            acc[0][0] += a4.x * b4.x; acc[0][1] += a4.x * b4.y;
            acc[0][2] += a4.x * b4.z; acc[0][3] += a4.x * b4.w;
            acc[1][0] += a4.y * b4.x; acc[1][1] += a4.y * b4.y;
            acc[1][2] += a4.y * b4.z; acc[1][3] += a4.y * b4.w;
            acc[2][0] += a4.z * b4.x; acc[2][1] += a4.z * b4.y;
            acc[2][2] += a4.z * b4.z; acc[2][3] += a4.z * b4.w;
            acc[3][0] += a4.w * b4.x; acc[3][1] += a4.w * b4.y;
            acc[3][2] += a4.w * b4.z; acc[3][3] += a4.w * b4.w;
        }
        __syncthreads();
    }
    float* Cp = C + (size_t)blockIdx.y * part_stride;
#pragma unroll
    for (int i = 0; i < 4; ++i) {
        int row = row0 + ty * 4 + i;
        if (row < M) {
            float4 v = make_float4(acc[i][0], acc[i][1], acc[i][2], acc[i][3]);
            *(float4*)(Cp + (size_t)row * 64 + tx * 4) = v;
        }
    }
}

// Sum split-K parts (p1 may be null), write combined h into p0 in-place,
// and compute a_s/a_d. One wave per row.
__global__ __launch_bounds__(256) void att_kernel(float* __restrict__ p0,
                                                  const float* __restrict__ p1,
                                                  const float* __restrict__ att_src,
                                                  const float* __restrict__ att_dst,
                                                  float* __restrict__ a_s,
                                                  float* __restrict__ a_d, int N) {
    int n = blockIdx.x * 4 + (threadIdx.x >> 6);
    int lane = threadIdx.x & 63;
    if (n >= N) return;
    size_t idx = (size_t)n * 64 + lane;
    float v = p0[idx];
    if (p1) {
        v += p1[idx];
        p0[idx] = v;
    }
    float s1 = wave_reduce_sum(v * att_src[lane]);
    float s2 = wave_reduce_sum(v * att_dst[lane]);
    if (lane == 0) { a_s[n] = s1; a_d[n] = s2; }
}

__device__ __forceinline__ void edge_sd(const int* __restrict__ ei, int E, int e,
                                        int& s, int& d) {
    if (e < E) { s = ei[e]; d = ei[E + e]; }
    else { s = d = e - E; }  // appended self-loops
}

// ---- CSR build ----
__global__ __launch_bounds__(256) void hist_kernel(const int* __restrict__ ei, int E,
                                                   int ET, int* __restrict__ counts) {
    int e = blockIdx.x * 256 + threadIdx.x;
    if (e >= ET) return;
    int s, d;
    edge_sd(ei, E, e, s, d);
    atomicAdd(counts + d, 1);
}

// single-block exclusive scan
__global__ __launch_bounds__(1024) void scan_kernel(const int* __restrict__ counts,
                                                    int* __restrict__ row_ptr, int N) {
    __shared__ int wsum[16];
    __shared__ int carry_s;
    const int tid = threadIdx.x;
    const int lane = tid & 63, wid = tid >> 6;
    if (tid == 0) carry_s = 0;
    __syncthreads();
    for (int base = 0; base < N; base += 1024) {
        int i = base + tid;
        int v = (i < N) ? counts[i] : 0;
        int sv = v;
#pragma unroll
        for (int off = 1; off < 64; off <<= 1) {
            int t = __shfl_up(sv, off, 64);
            if (lane >= off) sv += t;
        }
        if (lane == 63) wsum[wid] = sv;
        __syncthreads();
        if (wid == 0 && lane < 16) {
            int wv = wsum[lane];
#pragma unroll
            for (int off = 1; off < 16; off <<= 1) {
                int t = __shfl_up(wv, off, 64);
                if (lane >= off) wv += t;
            }
            wsum[lane] = wv;
        }
        __syncthreads();
        int excl = carry_s + (wid ? wsum[wid - 1] : 0) + sv - v;
        if (i < N) row_ptr[i] = excl;
        __syncthreads();
        if (tid == 1023) carry_s = excl + v;
        __syncthreads();
    }
    if (tid == 0) row_ptr[N] = carry_s;
}

__global__ __launch_bounds__(256) void fill_kernel(const int* __restrict__ ei, int E,
                                                   int ET, int* __restrict__ next,
                                                   int* __restrict__ srcs) {
    int e = blockIdx.x * 256 + threadIdx.x;
    if (e >= ET) return;
    int s, d;
    edge_sd(ei, E, e, s, d);
    int pos = atomicAdd(next + d, 1);
    srcs[pos] = s;
}

// ---- fused edge-softmax + aggregation + bias + relu: one wave per dst node ----
__global__ __launch_bounds__(256) void gat_agg_kernel(const int* __restrict__ row_ptr,
                                                      const int* __restrict__ srcs,
                                                      const float* __restrict__ a_s,
                                                      const float* __restrict__ a_d,
                                                      const float* __restrict__ h,
                                                      const float* __restrict__ bias,
                                                      float* __restrict__ out, int N) {
    int n = blockIdx.x * 4 + (threadIdx.x >> 6);
    int lane = threadIdx.x & 63;
    if (n >= N) return;
    const int start = row_ptr[n];
    const int end = row_ptr[n + 1];
    const float adn = a_d[n];

    float m = -1e30f;
    for (int i = start + lane; i < end; i += 64) {
        float v = a_s[srcs[i]] + adn;
        v = (v >= 0.f) ? v : NEG_SLOPE * v;
        m = fmaxf(m, v);
    }
    m = wave_reduce_max(m);

    float l = 0.f;
    for (int i = start + lane; i < end; i += 64) {
        float v = a_s[srcs[i]] + adn;
        v = (v >= 0.f) ? v : NEG_SLOPE * v;
        l += __expf(v - m);
    }
    l = wave_reduce_sum(l);
    const float inv_den = 1.f / l;

    float acc = 0.f;
    for (int c = start; c < end; c += 64) {
        int cl = end - c;
        if (cl > 64) cl = 64;
        int sl = 0;
        float wl = 0.f;
        if (c + lane < end) {
            sl = srcs[c + lane];
            float v = a_s[sl] + adn;
            v = (v >= 0.f) ? v : NEG_SLOPE * v;
            wl = __expf(v - m) * inv_den;
        }
        for (int j = 0; j < cl; ++j) {
            float wj = __shfl(wl, j, 64);
            int sj = __shfl(sl, j, 64);
            acc += wj * h[(size_t)sj * 64 + lane];
        }
    }
    float o = acc + bias[lane];
    out[(size_t)n * 64 + lane] = o > 0.f ? o : 0.f;
}

__global__ __launch_bounds__(256) void pool_kernel(const float* __restrict__ x,
                                                   const int* __restrict__ batch,
                                                   float* __restrict__ pooled,
                                                   float* __restrict__ cnt, int N) {
    int n = blockIdx.x * 4 + (threadIdx.x >> 6);
    int lane = threadIdx.x & 63;
    if (n >= N) return;
    int g = batch[n];
    atomicAdd(pooled + (size_t)g * 64 + lane, x[(size_t)n * 64 + lane]);
    if (lane == 0) atomicAdd(cnt + g, 1.0f);
}

__global__ __launch_bounds__(256) void final_kernel(const float* __restrict__ pooled,
                                                    const float* __restrict__ cnt,
                                                    const float* __restrict__ Wlin,
                                                    const float* __restrict__ blin,
                                                    float* __restrict__ out) {
    int g = blockIdx.x * 4 + (threadIdx.x >> 6);
    int lane = threadIdx.x & 63;
    if (g >= NGRAPHS) return;
    float c = cnt[g];
    c = c > 1.f ? c : 1.f;
    float p = pooled[(size_t)g * 64 + lane] / c;
    float o0 = wave_reduce_sum(p * Wlin[lane * 2 + 0]);
    float o1 = wave_reduce_sum(p * Wlin[lane * 2 + 1]);
    if (lane == 0) {
        out[g * 2 + 0] = o0 + blin[0];
        out[g * 2 + 1] = o1 + blin[1];
    }
}

extern "C" void kernel_launch(void* const* d_in, const int* in_sizes, int n_in,
                              void* d_out, int out_size, void* d_ws, size_t ws_size,
                              hipStream_t stream) {
    const float* x    = (const float*)d_in[0];
    const int*   ei   = (const int*)d_in[1];
    const int*   batch= (const int*)d_in[2];
    const float* W1   = (const float*)d_in[3];
    const float* as1  = (const float*)d_in[4];
    const float* ad1  = (const float*)d_in[5];
    const float* b1   = (const float*)d_in[6];
    const float* W2   = (const float*)d_in[7];
    const float* as2  = (const float*)d_in[8];
    const float* ad2  = (const float*)d_in[9];
    const float* b2   = (const float*)d_in[10];
    const float* Wlin = (const float*)d_in[11];
    const float* blin = (const float*)d_in[12];
    float* out = (float*)d_out;

    const int FIN = 768;
    const int N  = in_sizes[0] / FIN;   // 50000
    const int E  = in_sizes[1] / 2;     // 800000
    const int ET = E + N;
    const size_t N64 = (size_t)N * 64;

    // Workspace layout (same footprint as R2).
    // part1 of split-K gemm1 aliases x2 (dead until layer-2 epilogue).
    float* ws     = (float*)d_ws;
    float* hbuf   = ws;                          // N*64 (split part0 -> combined h)
    float* x1     = hbuf + N64;                  // N*64
    float* x2     = x1 + N64;                    // N*64 (aliases gemm1 split part1)
    float* a_s    = x2 + N64;                    // N
    float* a_d    = a_s + N;                     // N
    float* pooled = a_d + N;                     // 512*64
    float* cnt    = pooled + (size_t)NGRAPHS*64; // 512
    int* counts   = (int*)(cnt + NGRAPHS);       // N
    int* row_ptr  = counts + N;                  // N+1
    int* next     = row_ptr + N + 1;             // N
    int* srcs     = next + N;                    // ET

    const int nEdgeBlk  = (ET + 255) / 256;
    const int nWaveBlkN = (N + 3) / 4;
    const int nGemmBlk  = (N + 63) / 64;

    hipMemsetAsync(pooled, 0,
                   ((size_t)NGRAPHS * 64 + NGRAPHS + N) * sizeof(float), stream);

    // ---- CSR build (by destination), reused by both layers ----
    hist_kernel<<<nEdgeBlk, 256, 0, stream>>>(ei, E, ET, counts);
    scan_kernel<<<1, 1024, 0, stream>>>(counts, row_ptr, N);
    hipMemcpyAsync(next, row_ptr, (size_t)N * sizeof(int),
                   hipMemcpyDeviceToDevice, stream);
    fill_kernel<<<nEdgeBlk, 256, 0, stream>>>(ei, E, ET, next, srcs);

    // ---- Layer 1: split-K=2 gemm (K=768 -> 2x384), parts summed in att ----
    gemm64s<<<dim3(nGemmBlk, 2), 256, 0, stream>>>(x, W1, hbuf, N, FIN, FIN / 2,
                                                   2 * N64 /* hbuf -> x2 */);
    att_kernel<<<nWaveBlkN, 256, 0, stream>>>(hbuf, x2, as1, ad1, a_s, a_d, N);
    gat_agg_kernel<<<nWaveBlkN, 256, 0, stream>>>(row_ptr, srcs, a_s, a_d, hbuf,
                                                  b1, x1, N);

    // ---- Layer 2 (K=64, no split) ----
    gemm64s<<<dim3(nGemmBlk, 1), 256, 0, stream>>>(x1, W2, hbuf, N, 64, 64, 0);
    att_kernel<<<nWaveBlkN, 256, 0, stream>>>(hbuf, nullptr, as2, ad2, a_s, a_d, N);
    gat_agg_kernel<<<nWaveBlkN, 256, 0, stream>>>(row_ptr, srcs, a_s, a_d, hbuf,
                                                  b2, x2, N);

    // ---- Pool + linear ----
    pool_kernel<<<nWaveBlkN, 256, 0, stream>>>(x2, batch, pooled, cnt, N);
    final_kernel<<<(NGRAPHS + 3) / 4, 256, 0, stream>>>(pooled, cnt, Wlin, blin, out);
}

// Round 4
// 597.002 us; speedup vs baseline: 1.6478x; 1.1465x over previous
//
#include <hip/hip_runtime.h>

#define NEG_SLOPE 0.2f
#define NGRAPHS 512

typedef short short8 __attribute__((ext_vector_type(8)));
typedef float f32x4 __attribute__((ext_vector_type(4)));

__device__ __forceinline__ float wave_reduce_sum(float v) {
#pragma unroll
    for (int off = 32; off > 0; off >>= 1) v += __shfl_xor(v, off, 64);
    return v;
}
__device__ __forceinline__ float wave_reduce_max(float v) {
#pragma unroll
    for (int off = 32; off > 0; off >>= 1) v = fmaxf(v, __shfl_xor(v, off, 64));
    return v;
}
__device__ __forceinline__ unsigned short f2bf(float f) {  // fp32 -> bf16 RNE
    unsigned u = __float_as_uint(f);
    u += 0x7FFFu + ((u >> 16) & 1u);
    return (unsigned short)(u >> 16);
}

// W[K][64] fp32 -> Wt[64][K] bf16 (transposed). One block per output col n.
__global__ __launch_bounds__(256) void convert_w(const float* __restrict__ W,
                                                 unsigned short* __restrict__ Wt,
                                                 int K) {
    int n = blockIdx.x;
    for (int k = threadIdx.x; k < K; k += 256)
        Wt[(size_t)n * K + k] = f2bf(W[(size_t)k * 64 + n]);
}

// h[M,64] = A[M,K](fp32->bf16) @ Wt^T (Wt is [64][K] bf16), MFMA 16x16x32.
// Fused epilogue: a_s[r] = h[r,:]·att_s ; a_d[r] = h[r,:]·att_d.
__global__ __launch_bounds__(256) void gemm_att_mfma(
    const float* __restrict__ A, const unsigned short* __restrict__ Wt, int M, int K,
    float* __restrict__ h, const float* __restrict__ att_s,
    const float* __restrict__ att_d, float* __restrict__ a_s,
    float* __restrict__ a_d) {
    __shared__ unsigned short As[64][72];  // +8 pad: conflict-free b128 frag reads
    const int tid = threadIdx.x;
    const int w = tid >> 6, l = tid & 63, m = l & 15, q = l >> 4;
    const int row0 = blockIdx.x * 64;
    f32x4 acc0 = {0.f, 0.f, 0.f, 0.f}, acc1 = acc0, acc2 = acc0, acc3 = acc0;
    const int sr = tid >> 2, sc = tid & 3;  // staging: row 0..63, 16-elem k-chunk 0..3
    const int grow = row0 + sr;
    const bool rok = grow < M;
    if (!rok) {
#pragma unroll
        for (int j = 0; j < 16; ++j) As[sr][sc * 16 + j] = 0;
    }
    const float* Ap = A + (size_t)grow * K + sc * 16;

    for (int k0 = 0; k0 < K; k0 += 64) {
        if (rok) {
            const float4* p = (const float4*)(Ap + k0);
            float4 f0 = p[0], f1 = p[1], f2 = p[2], f3 = p[3];
            unsigned short t[16] = {
                f2bf(f0.x), f2bf(f0.y), f2bf(f0.z), f2bf(f0.w),
                f2bf(f1.x), f2bf(f1.y), f2bf(f1.z), f2bf(f1.w),
                f2bf(f2.x), f2bf(f2.y), f2bf(f2.z), f2bf(f2.w),
                f2bf(f3.x), f2bf(f3.y), f2bf(f3.z), f2bf(f3.w)};
            *(uint4*)&As[sr][sc * 16] = *(uint4*)&t[0];
            *(uint4*)&As[sr][sc * 16 + 8] = *(uint4*)&t[8];
        }
        __syncthreads();
        const unsigned short* arow = &As[w * 16 + m][0];
        const unsigned short* brow = Wt + (size_t)m * K + k0;
#pragma unroll
        for (int kk = 0; kk < 2; ++kk) {
            short8 av = *(const short8*)(arow + kk * 32 + q * 8);
            const unsigned short* bp = brow + kk * 32 + q * 8;
            acc0 = __builtin_amdgcn_mfma_f32_16x16x32_bf16(
                av, *(const short8*)(bp), acc0, 0, 0, 0);
            acc1 = __builtin_amdgcn_mfma_f32_16x16x32_bf16(
                av, *(const short8*)(bp + (size_t)16 * K), acc1, 0, 0, 0);
            acc2 = __builtin_amdgcn_mfma_f32_16x16x32_bf16(
                av, *(const short8*)(bp + (size_t)32 * K), acc2, 0, 0, 0);
            acc3 = __builtin_amdgcn_mfma_f32_16x16x32_bf16(
                av, *(const short8*)(bp + (size_t)48 * K), acc3, 0, 0, 0);
        }
        __syncthreads();
    }
    // epilogue: C/D layout col=lane&15, row=q*4+reg (per 16-col group)
    float as0 = att_s[m], as1 = att_s[16 + m], as2 = att_s[32 + m], as3 = att_s[48 + m];
    float ad0 = att_d[m], ad1 = att_d[16 + m], ad2 = att_d[32 + m], ad3 = att_d[48 + m];
    const int rowb = row0 + w * 16 + q * 4;
#pragma unroll
    for (int r = 0; r < 4; ++r) {
        int row = rowb + r;
        float v0 = acc0[r], v1 = acc1[r], v2 = acc2[r], v3 = acc3[r];
        if (row < M) {
            float* hp = h + (size_t)row * 64 + m;
            hp[0] = v0; hp[16] = v1; hp[32] = v2; hp[48] = v3;
        }
        float hs = v0 * as0 + v1 * as1 + v2 * as2 + v3 * as3;
        float hd = v0 * ad0 + v1 * ad1 + v2 * ad2 + v3 * ad3;
#pragma unroll
        for (int off = 1; off < 16; off <<= 1) {
            hs += __shfl_xor(hs, off, 64);
            hd += __shfl_xor(hd, off, 64);
        }
        if (m == 0 && row < M) { a_s[row] = hs; a_d[row] = hd; }
    }
}

// fp32 GEMM (layer 2, K=64) with fused att epilogue. As k-major (conflict-free).
__global__ __launch_bounds__(256) void gemm64s(const float* __restrict__ A,
                                               const float* __restrict__ B,
                                               float* __restrict__ C, int M, int K,
                                               const float* __restrict__ att_s,
                                               const float* __restrict__ att_d,
                                               float* __restrict__ a_s,
                                               float* __restrict__ a_d) {
    __shared__ float As[16][64];
    __shared__ float Bs[16][64];
    const int tid = threadIdx.x;
    const int tx = tid & 15;
    const int ty = tid >> 4;
    const int row0 = blockIdx.x * 64;
    float acc[4][4] = {};
    const int la_row = tid >> 2;
    const int la_col = (tid & 3) * 4;
    const int lb_row = tid >> 4;
    const int lb_col = (tid & 15) * 4;

    for (int k0 = 0; k0 < K; k0 += 16) {
        int ar = row0 + la_row;
        float4 av = make_float4(0.f, 0.f, 0.f, 0.f);
        if (ar < M) av = *(const float4*)(A + (size_t)ar * K + k0 + la_col);
        As[la_col + 0][la_row] = av.x;
        As[la_col + 1][la_row] = av.y;
        As[la_col + 2][la_row] = av.z;
        As[la_col + 3][la_row] = av.w;
        *(float4*)&Bs[lb_row][lb_col] =
            *(const float4*)(B + (size_t)(k0 + lb_row) * 64 + lb_col);
        __syncthreads();
#pragma unroll
        for (int k = 0; k < 16; ++k) {
            float4 a4 = *(float4*)&As[k][ty * 4];
            float4 b4 = *(float4*)&Bs[k][tx * 4];
            acc[0][0] += a4.x * b4.x; acc[0][1] += a4.x * b4.y;
            acc[0][2] += a4.x * b4.z; acc[0][3] += a4.x * b4.w;
            acc[1][0] += a4.y * b4.x; acc[1][1] += a4.y * b4.y;
            acc[1][2] += a4.y * b4.z; acc[1][3] += a4.y * b4.w;
            acc[2][0] += a4.z * b4.x; acc[2][1] += a4.z * b4.y;
            acc[2][2] += a4.z * b4.z; acc[2][3] += a4.z * b4.w;
            acc[3][0] += a4.w * b4.x; acc[3][1] += a4.w * b4.y;
            acc[3][2] += a4.w * b4.z; acc[3][3] += a4.w * b4.w;
        }
        __syncthreads();
    }
    float asv[4], adv[4];
#pragma unroll
    for (int j = 0; j < 4; ++j) {
        asv[j] = att_s[tx * 4 + j];
        adv[j] = att_d[tx * 4 + j];
    }
#pragma unroll
    for (int i = 0; i < 4; ++i) {
        int row = row0 + ty * 4 + i;
        if (row < M) {
            float4 v = make_float4(acc[i][0], acc[i][1], acc[i][2], acc[i][3]);
            *(float4*)(C + (size_t)row * 64 + tx * 4) = v;
        }
        float hs = acc[i][0] * asv[0] + acc[i][1] * asv[1] +
                   acc[i][2] * asv[2] + acc[i][3] * asv[3];
        float hd = acc[i][0] * adv[0] + acc[i][1] * adv[1] +
                   acc[i][2] * adv[2] + acc[i][3] * adv[3];
#pragma unroll
        for (int off = 1; off < 16; off <<= 1) {
            hs += __shfl_xor(hs, off, 64);
            hd += __shfl_xor(hd, off, 64);
        }
        if (tx == 0 && row < M) { a_s[row] = hs; a_d[row] = hd; }
    }
}

__device__ __forceinline__ void edge_sd(const int* __restrict__ ei, int E, int e,
                                        int& s, int& d) {
    if (e < E) { s = ei[e]; d = ei[E + e]; }
    else { s = d = e - E; }
}

// ---- CSR build ----
__global__ __launch_bounds__(256) void hist_kernel(const int* __restrict__ ei, int E,
                                                   int ET, int* __restrict__ counts) {
    int e = blockIdx.x * 256 + threadIdx.x;
    if (e >= ET) return;
    int s, d;
    edge_sd(ei, E, e, s, d);
    atomicAdd(counts + d, 1);
}

// per-block sums over chunks of CH
__global__ __launch_bounds__(256) void scan_sum(const int* __restrict__ counts,
                                                int* __restrict__ blk_sum, int N,
                                                int CH) {
    __shared__ int wsum[4];
    const int tid = threadIdx.x, lane = tid & 63, wid = tid >> 6;
    const int b = blockIdx.x;
    int begin = b * CH, endi = min(begin + CH, N);
    int s = 0;
    for (int i = begin + tid; i < endi; i += 256) s += counts[i];
#pragma unroll
    for (int off = 32; off > 0; off >>= 1) s += __shfl_xor(s, off, 64);
    if (lane == 0) wsum[wid] = s;
    __syncthreads();
    if (tid == 0) blk_sum[b] = wsum[0] + wsum[1] + wsum[2] + wsum[3];
}

// exclusive scan of 64 block sums (1 wave); also writes row_ptr[N]=total
__global__ __launch_bounds__(64) void scan_blk(int* __restrict__ blk_sum,
                                               int* __restrict__ row_ptr, int N,
                                               int nb) {
    int t = threadIdx.x;
    int v = (t < nb) ? blk_sum[t] : 0;
    int sv = v;
#pragma unroll
    for (int off = 1; off < 64; off <<= 1) {
        int u = __shfl_up(sv, off, 64);
        if (t >= off) sv += u;
    }
    if (t < nb) blk_sum[t] = sv - v;
    if (t == nb - 1) row_ptr[N] = sv;
}

// local exclusive scan with block offset; writes row_ptr AND next
__global__ __launch_bounds__(256) void scan_local(const int* __restrict__ counts,
                                                  const int* __restrict__ blk_off,
                                                  int* __restrict__ row_ptr,
                                                  int* __restrict__ next_, int N,
                                                  int CH) {
    __shared__ int wsum[4];
    __shared__ int ctot;
    const int tid = threadIdx.x, lane = tid & 63, wid = tid >> 6;
    const int b = blockIdx.x;
    int begin = b * CH, endi = min(begin + CH, N);
    int carry = blk_off[b];
    for (int base = begin; base < endi; base += 256) {
        int i = base + tid;
        int v = (i < endi) ? counts[i] : 0;
        int sv = v;
#pragma unroll
        for (int off = 1; off < 64; off <<= 1) {
            int u = __shfl_up(sv, off, 64);
            if (lane >= off) sv += u;
        }
        if (lane == 63) wsum[wid] = sv;
        __syncthreads();
        if (tid == 0) {
            int a = 0;
#pragma unroll
            for (int j = 0; j < 4; ++j) { int u = wsum[j]; wsum[j] = a; a += u; }
            ctot = a;
        }
        __syncthreads();
        int excl = carry + wsum[wid] + sv - v;
        if (i < endi) { row_ptr[i] = excl; next_[i] = excl; }
        carry += ctot;
        __syncthreads();
    }
}

__global__ __launch_bounds__(256) void fill_kernel(const int* __restrict__ ei, int E,
                                                   int ET, int* __restrict__ next,
                                                   int* __restrict__ srcs) {
    int e = blockIdx.x * 256 + threadIdx.x;
    if (e >= ET) return;
    int s, d;
    edge_sd(ei, E, e, s, d);
    int pos = atomicAdd(next + d, 1);
    srcs[pos] = s;
}

// ---- fused edge-softmax + aggregation + bias + relu: one wave per dst node ----
__global__ __launch_bounds__(256) void gat_agg_kernel(const int* __restrict__ row_ptr,
                                                      const int* __restrict__ srcs,
                                                      const float* __restrict__ a_s,
                                                      const float* __restrict__ a_d,
                                                      const float* __restrict__ h,
                                                      const float* __restrict__ bias,
                                                      float* __restrict__ out, int N) {
    int n = blockIdx.x * 4 + (threadIdx.x >> 6);
    int lane = threadIdx.x & 63;
    if (n >= N) return;
    const int start = row_ptr[n];
    const int end = row_ptr[n + 1];
    const float adn = a_d[n];

    float m = -1e30f;
    for (int i = start + lane; i < end; i += 64) {
        float v = a_s[srcs[i]] + adn;
        v = (v >= 0.f) ? v : NEG_SLOPE * v;
        m = fmaxf(m, v);
    }
    m = wave_reduce_max(m);

    float l = 0.f;
    for (int i = start + lane; i < end; i += 64) {
        float v = a_s[srcs[i]] + adn;
        v = (v >= 0.f) ? v : NEG_SLOPE * v;
        l += __expf(v - m);
    }
    l = wave_reduce_sum(l);
    const float inv_den = 1.f / l;

    float acc = 0.f;
    for (int c = start; c < end; c += 64) {
        int cl = end - c;
        if (cl > 64) cl = 64;
        int sl = 0;
        float wl = 0.f;
        if (c + lane < end) {
            sl = srcs[c + lane];
            float v = a_s[sl] + adn;
            v = (v >= 0.f) ? v : NEG_SLOPE * v;
            wl = __expf(v - m) * inv_den;
        }
        for (int j = 0; j < cl; ++j) {
            float wj = __shfl(wl, j, 64);
            int sj = __shfl(sl, j, 64);
            acc += wj * h[(size_t)sj * 64 + lane];
        }
    }
    float o = acc + bias[lane];
    out[(size_t)n * 64 + lane] = o > 0.f ? o : 0.f;
}

__global__ __launch_bounds__(256) void pool_kernel(const float* __restrict__ x,
                                                   const int* __restrict__ batch,
                                                   float* __restrict__ pooled,
                                                   float* __restrict__ cnt, int N) {
    int n = blockIdx.x * 4 + (threadIdx.x >> 6);
    int lane = threadIdx.x & 63;
    if (n >= N) return;
    int g = batch[n];
    atomicAdd(pooled + (size_t)g * 64 + lane, x[(size_t)n * 64 + lane]);
    if (lane == 0) atomicAdd(cnt + g, 1.0f);
}

__global__ __launch_bounds__(256) void final_kernel(const float* __restrict__ pooled,
                                                    const float* __restrict__ cnt,
                                                    const float* __restrict__ Wlin,
                                                    const float* __restrict__ blin,
                                                    float* __restrict__ out) {
    int g = blockIdx.x * 4 + (threadIdx.x >> 6);
    int lane = threadIdx.x & 63;
    if (g >= NGRAPHS) return;
    float c = cnt[g];
    c = c > 1.f ? c : 1.f;
    float p = pooled[(size_t)g * 64 + lane] / c;
    float o0 = wave_reduce_sum(p * Wlin[lane * 2 + 0]);
    float o1 = wave_reduce_sum(p * Wlin[lane * 2 + 1]);
    if (lane == 0) {
        out[g * 2 + 0] = o0 + blin[0];
        out[g * 2 + 1] = o1 + blin[1];
    }
}

extern "C" void kernel_launch(void* const* d_in, const int* in_sizes, int n_in,
                              void* d_out, int out_size, void* d_ws, size_t ws_size,
                              hipStream_t stream) {
    const float* x    = (const float*)d_in[0];
    const int*   ei   = (const int*)d_in[1];
    const int*   batch= (const int*)d_in[2];
    const float* W1   = (const float*)d_in[3];
    const float* as1  = (const float*)d_in[4];
    const float* ad1  = (const float*)d_in[5];
    const float* b1   = (const float*)d_in[6];
    const float* W2   = (const float*)d_in[7];
    const float* as2  = (const float*)d_in[8];
    const float* ad2  = (const float*)d_in[9];
    const float* b2   = (const float*)d_in[10];
    const float* Wlin = (const float*)d_in[11];
    const float* blin = (const float*)d_in[12];
    float* out = (float*)d_out;

    const int FIN = 768;
    const int N  = in_sizes[0] / FIN;   // 50000
    const int E  = in_sizes[1] / 2;     // 800000
    const int ET = E + N;
    const size_t N64 = (size_t)N * 64;
    const int NB = 64;                  // scan blocks
    const int CH = (N + NB - 1) / NB;

    float* ws     = (float*)d_ws;
    float* hbuf   = ws;                          // N*64
    float* x1     = hbuf + N64;                  // N*64
    float* x2     = x1 + N64;                    // N*64
    float* a_s    = x2 + N64;                    // N
    float* a_d    = a_s + N;                     // N
    float* pooled = a_d + N;                     // 512*64
    float* cnt    = pooled + (size_t)NGRAPHS*64; // 512
    int* counts   = (int*)(cnt + NGRAPHS);       // N   (zeroed with pooled/cnt)
    int* row_ptr  = counts + N;                  // N+1
    int* next     = row_ptr + N + 1;             // N
    int* blk_sum  = next + N;                    // 64
    int* srcs     = blk_sum + 64;                // ET
    // 16B-align the bf16 weight buffers
    uintptr_t wtp = (uintptr_t)(srcs + ET);
    wtp = (wtp + 15) & ~(uintptr_t)15;
    unsigned short* Wt1 = (unsigned short*)wtp;          // 64*768
    unsigned short* Wt2 = Wt1 + (size_t)64 * FIN;        // 64*64

    const int nEdgeBlk  = (ET + 255) / 256;
    const int nWaveBlkN = (N + 3) / 4;
    const int nGemmBlk  = (N + 63) / 64;

    hipMemsetAsync(pooled, 0,
                   ((size_t)NGRAPHS * 64 + NGRAPHS + N) * sizeof(float), stream);

    // ---- weight convert (tiny) ----
    convert_w<<<64, 256, 0, stream>>>(W1, Wt1, FIN);
    convert_w<<<64, 256, 0, stream>>>(W2, Wt2, 64);

    // ---- CSR build (by destination), reused by both layers ----
    hist_kernel<<<nEdgeBlk, 256, 0, stream>>>(ei, E, ET, counts);
    scan_sum<<<NB, 256, 0, stream>>>(counts, blk_sum, N, CH);
    scan_blk<<<1, 64, 0, stream>>>(blk_sum, row_ptr, N, NB);
    scan_local<<<NB, 256, 0, stream>>>(counts, blk_sum, row_ptr, next, N, CH);
    fill_kernel<<<nEdgeBlk, 256, 0, stream>>>(ei, E, ET, next, srcs);

    // ---- Layer 1: bf16 MFMA gemm + fused att ----
    gemm_att_mfma<<<nGemmBlk, 256, 0, stream>>>(x, Wt1, N, FIN, hbuf, as1, ad1,
                                                a_s, a_d);
    gat_agg_kernel<<<nWaveBlkN, 256, 0, stream>>>(row_ptr, srcs, a_s, a_d, hbuf,
                                                  b1, x1, N);

    // ---- Layer 2: fp32 gemm (K=64) + fused att ----
    gemm64s<<<nGemmBlk, 256, 0, stream>>>(x1, W2, hbuf, N, 64, as2, ad2, a_s, a_d);
    gat_agg_kernel<<<nWaveBlkN, 256, 0, stream>>>(row_ptr, srcs, a_s, a_d, hbuf,
                                                  b2, x2, N);

    // ---- Pool + linear ----
    pool_kernel<<<nWaveBlkN, 256, 0, stream>>>(x2, batch, pooled, cnt, N);
    final_kernel<<<(NGRAPHS + 3) / 4, 256, 0, stream>>>(pooled, cnt, Wlin, blin, out);
}

// Round 5
// 540.555 us; speedup vs baseline: 1.8198x; 1.1044x over previous
//
#include <hip/hip_runtime.h>

#define NEG_SLOPE 0.2f
#define NGRAPHS 512

typedef short short8 __attribute__((ext_vector_type(8)));
typedef float f32x4 __attribute__((ext_vector_type(4)));

__device__ __forceinline__ float wave_reduce_sum(float v) {
#pragma unroll
    for (int off = 32; off > 0; off >>= 1) v += __shfl_xor(v, off, 64);
    return v;
}
__device__ __forceinline__ float wave_reduce_max(float v) {
#pragma unroll
    for (int off = 32; off > 0; off >>= 1) v = fmaxf(v, __shfl_xor(v, off, 64));
    return v;
}
__device__ __forceinline__ unsigned short f2bf(float f) {  // fp32 -> bf16 RNE
    unsigned u = __float_as_uint(f);
    u += 0x7FFFu + ((u >> 16) & 1u);
    return (unsigned short)(u >> 16);
}

// W[K][64] fp32 -> Wt[64][K] bf16 (transposed). One block per output col n.
__global__ __launch_bounds__(256) void convert_w(const float* __restrict__ W,
                                                 unsigned short* __restrict__ Wt,
                                                 int K) {
    int n = blockIdx.x;
    for (int k = threadIdx.x; k < K; k += 256)
        Wt[(size_t)n * K + k] = f2bf(W[(size_t)k * 64 + n]);
}

// h[M,64] = A[M,K](fp32->bf16) @ Wt^T (Wt is [64][K] bf16), MFMA 16x16x32.
// Fused epilogue: a_s[r] = h[r,:]·att_s ; a_d[r] = h[r,:]·att_d.
__global__ __launch_bounds__(256) void gemm_att_mfma(
    const float* __restrict__ A, const unsigned short* __restrict__ Wt, int M, int K,
    float* __restrict__ h, const float* __restrict__ att_s,
    const float* __restrict__ att_d, float* __restrict__ a_s,
    float* __restrict__ a_d) {
    __shared__ unsigned short As[64][72];  // +8 pad: conflict-free b128 frag reads
    const int tid = threadIdx.x;
    const int w = tid >> 6, l = tid & 63, m = l & 15, q = l >> 4;
    const int row0 = blockIdx.x * 64;
    f32x4 acc0 = {0.f, 0.f, 0.f, 0.f}, acc1 = acc0, acc2 = acc0, acc3 = acc0;
    const int sr = tid >> 2, sc = tid & 3;  // staging: row 0..63, 16-elem k-chunk 0..3
    const int grow = row0 + sr;
    const bool rok = grow < M;
    if (!rok) {
#pragma unroll
        for (int j = 0; j < 16; ++j) As[sr][sc * 16 + j] = 0;
    }
    const float* Ap = A + (size_t)grow * K + sc * 16;

    for (int k0 = 0; k0 < K; k0 += 64) {
        if (rok) {
            const float4* p = (const float4*)(Ap + k0);
            float4 f0 = p[0], f1 = p[1], f2 = p[2], f3 = p[3];
            unsigned short t[16] = {
                f2bf(f0.x), f2bf(f0.y), f2bf(f0.z), f2bf(f0.w),
                f2bf(f1.x), f2bf(f1.y), f2bf(f1.z), f2bf(f1.w),
                f2bf(f2.x), f2bf(f2.y), f2bf(f2.z), f2bf(f2.w),
                f2bf(f3.x), f2bf(f3.y), f2bf(f3.z), f2bf(f3.w)};
            *(uint4*)&As[sr][sc * 16] = *(uint4*)&t[0];
            *(uint4*)&As[sr][sc * 16 + 8] = *(uint4*)&t[8];
        }
        __syncthreads();
        const unsigned short* arow = &As[w * 16 + m][0];
        const unsigned short* brow = Wt + (size_t)m * K + k0;
#pragma unroll
        for (int kk = 0; kk < 2; ++kk) {
            short8 av = *(const short8*)(arow + kk * 32 + q * 8);
            const unsigned short* bp = brow + kk * 32 + q * 8;
            acc0 = __builtin_amdgcn_mfma_f32_16x16x32_bf16(
                av, *(const short8*)(bp), acc0, 0, 0, 0);
            acc1 = __builtin_amdgcn_mfma_f32_16x16x32_bf16(
                av, *(const short8*)(bp + (size_t)16 * K), acc1, 0, 0, 0);
            acc2 = __builtin_amdgcn_mfma_f32_16x16x32_bf16(
                av, *(const short8*)(bp + (size_t)32 * K), acc2, 0, 0, 0);
            acc3 = __builtin_amdgcn_mfma_f32_16x16x32_bf16(
                av, *(const short8*)(bp + (size_t)48 * K), acc3, 0, 0, 0);
        }
        __syncthreads();
    }
    // epilogue: C/D layout col=lane&15, row=q*4+reg (per 16-col group)
    float as0 = att_s[m], as1 = att_s[16 + m], as2 = att_s[32 + m], as3 = att_s[48 + m];
    float ad0 = att_d[m], ad1 = att_d[16 + m], ad2 = att_d[32 + m], ad3 = att_d[48 + m];
    const int rowb = row0 + w * 16 + q * 4;
#pragma unroll
    for (int r = 0; r < 4; ++r) {
        int row = rowb + r;
        float v0 = acc0[r], v1 = acc1[r], v2 = acc2[r], v3 = acc3[r];
        if (row < M) {
            float* hp = h + (size_t)row * 64 + m;
            hp[0] = v0; hp[16] = v1; hp[32] = v2; hp[48] = v3;
        }
        float hs = v0 * as0 + v1 * as1 + v2 * as2 + v3 * as3;
        float hd = v0 * ad0 + v1 * ad1 + v2 * ad2 + v3 * ad3;
#pragma unroll
        for (int off = 1; off < 16; off <<= 1) {
            hs += __shfl_xor(hs, off, 64);
            hd += __shfl_xor(hd, off, 64);
        }
        if (m == 0 && row < M) { a_s[row] = hs; a_d[row] = hd; }
    }
}

// fp32 GEMM (layer 2, K=64) with fused att epilogue. As k-major (conflict-free).
__global__ __launch_bounds__(256) void gemm64s(const float* __restrict__ A,
                                               const float* __restrict__ B,
                                               float* __restrict__ C, int M, int K,
                                               const float* __restrict__ att_s,
                                               const float* __restrict__ att_d,
                                               float* __restrict__ a_s,
                                               float* __restrict__ a_d) {
    __shared__ float As[16][64];
    __shared__ float Bs[16][64];
    const int tid = threadIdx.x;
    const int tx = tid & 15;
    const int ty = tid >> 4;
    const int row0 = blockIdx.x * 64;
    float acc[4][4] = {};
    const int la_row = tid >> 2;
    const int la_col = (tid & 3) * 4;
    const int lb_row = tid >> 4;
    const int lb_col = (tid & 15) * 4;

    for (int k0 = 0; k0 < K; k0 += 16) {
        int ar = row0 + la_row;
        float4 av = make_float4(0.f, 0.f, 0.f, 0.f);
        if (ar < M) av = *(const float4*)(A + (size_t)ar * K + k0 + la_col);
        As[la_col + 0][la_row] = av.x;
        As[la_col + 1][la_row] = av.y;
        As[la_col + 2][la_row] = av.z;
        As[la_col + 3][la_row] = av.w;
        *(float4*)&Bs[lb_row][lb_col] =
            *(const float4*)(B + (size_t)(k0 + lb_row) * 64 + lb_col);
        __syncthreads();
#pragma unroll
        for (int k = 0; k < 16; ++k) {
            float4 a4 = *(float4*)&As[k][ty * 4];
            float4 b4 = *(float4*)&Bs[k][tx * 4];
            acc[0][0] += a4.x * b4.x; acc[0][1] += a4.x * b4.y;
            acc[0][2] += a4.x * b4.z; acc[0][3] += a4.x * b4.w;
            acc[1][0] += a4.y * b4.x; acc[1][1] += a4.y * b4.y;
            acc[1][2] += a4.y * b4.z; acc[1][3] += a4.y * b4.w;
            acc[2][0] += a4.z * b4.x; acc[2][1] += a4.z * b4.y;
            acc[2][2] += a4.z * b4.z; acc[2][3] += a4.z * b4.w;
            acc[3][0] += a4.w * b4.x; acc[3][1] += a4.w * b4.y;
            acc[3][2] += a4.w * b4.z; acc[3][3] += a4.w * b4.w;
        }
        __syncthreads();
    }
    float asv[4], adv[4];
#pragma unroll
    for (int j = 0; j < 4; ++j) {
        asv[j] = att_s[tx * 4 + j];
        adv[j] = att_d[tx * 4 + j];
    }
#pragma unroll
    for (int i = 0; i < 4; ++i) {
        int row = row0 + ty * 4 + i;
        if (row < M) {
            float4 v = make_float4(acc[i][0], acc[i][1], acc[i][2], acc[i][3]);
            *(float4*)(C + (size_t)row * 64 + tx * 4) = v;
        }
        float hs = acc[i][0] * asv[0] + acc[i][1] * asv[1] +
                   acc[i][2] * asv[2] + acc[i][3] * asv[3];
        float hd = acc[i][0] * adv[0] + acc[i][1] * adv[1] +
                   acc[i][2] * adv[2] + acc[i][3] * adv[3];
#pragma unroll
        for (int off = 1; off < 16; off <<= 1) {
            hs += __shfl_xor(hs, off, 64);
            hd += __shfl_xor(hd, off, 64);
        }
        if (tx == 0 && row < M) { a_s[row] = hs; a_d[row] = hd; }
    }
}

__device__ __forceinline__ void edge_sd(const int* __restrict__ ei, int E, int e,
                                        int& s, int& d) {
    if (e < E) { s = ei[e]; d = ei[E + e]; }
    else { s = d = e - E; }
}

// ---- CSR build ----
__global__ __launch_bounds__(256) void hist_kernel(const int* __restrict__ ei, int E,
                                                   int ET, int* __restrict__ counts) {
    int e = blockIdx.x * 256 + threadIdx.x;
    if (e >= ET) return;
    int s, d;
    edge_sd(ei, E, e, s, d);
    atomicAdd(counts + d, 1);
}

// per-block sums over chunks of CH
__global__ __launch_bounds__(256) void scan_sum(const int* __restrict__ counts,
                                                int* __restrict__ blk_sum, int N,
                                                int CH) {
    __shared__ int wsum[4];
    const int tid = threadIdx.x, lane = tid & 63, wid = tid >> 6;
    const int b = blockIdx.x;
    int begin = b * CH, endi = min(begin + CH, N);
    int s = 0;
    for (int i = begin + tid; i < endi; i += 256) s += counts[i];
#pragma unroll
    for (int off = 32; off > 0; off >>= 1) s += __shfl_xor(s, off, 64);
    if (lane == 0) wsum[wid] = s;
    __syncthreads();
    if (tid == 0) blk_sum[b] = wsum[0] + wsum[1] + wsum[2] + wsum[3];
}

// exclusive scan of 64 block sums (1 wave); also writes row_ptr[N]=total
__global__ __launch_bounds__(64) void scan_blk(int* __restrict__ blk_sum,
                                               int* __restrict__ row_ptr, int N,
                                               int nb) {
    int t = threadIdx.x;
    int v = (t < nb) ? blk_sum[t] : 0;
    int sv = v;
#pragma unroll
    for (int off = 1; off < 64; off <<= 1) {
        int u = __shfl_up(sv, off, 64);
        if (t >= off) sv += u;
    }
    if (t < nb) blk_sum[t] = sv - v;
    if (t == nb - 1) row_ptr[N] = sv;
}

// local exclusive scan with block offset; writes row_ptr AND next
__global__ __launch_bounds__(256) void scan_local(const int* __restrict__ counts,
                                                  const int* __restrict__ blk_off,
                                                  int* __restrict__ row_ptr,
                                                  int* __restrict__ next_, int N,
                                                  int CH) {
    __shared__ int wsum[4];
    __shared__ int ctot;
    const int tid = threadIdx.x, lane = tid & 63, wid = tid >> 6;
    const int b = blockIdx.x;
    int begin = b * CH, endi = min(begin + CH, N);
    int carry = blk_off[b];
    for (int base = begin; base < endi; base += 256) {
        int i = base + tid;
        int v = (i < endi) ? counts[i] : 0;
        int sv = v;
#pragma unroll
        for (int off = 1; off < 64; off <<= 1) {
            int u = __shfl_up(sv, off, 64);
            if (lane >= off) sv += u;
        }
        if (lane == 63) wsum[wid] = sv;
        __syncthreads();
        if (tid == 0) {
            int a = 0;
#pragma unroll
            for (int j = 0; j < 4; ++j) { int u = wsum[j]; wsum[j] = a; a += u; }
            ctot = a;
        }
        __syncthreads();
        int excl = carry + wsum[wid] + sv - v;
        if (i < endi) { row_ptr[i] = excl; next_[i] = excl; }
        carry += ctot;
        __syncthreads();
    }
}

__global__ __launch_bounds__(256) void fill_kernel(const int* __restrict__ ei, int E,
                                                   int ET, int* __restrict__ next,
                                                   int* __restrict__ srcs) {
    int e = blockIdx.x * 256 + threadIdx.x;
    if (e >= ET) return;
    int s, d;
    edge_sd(ei, E, e, s, d);
    int pos = atomicAdd(next + d, 1);
    srcs[pos] = s;
}

// ---- fused edge-softmax + aggregation + bias + relu: one wave per dst node ----
__global__ __launch_bounds__(256) void gat_agg_kernel(const int* __restrict__ row_ptr,
                                                      const int* __restrict__ srcs,
                                                      const float* __restrict__ a_s,
                                                      const float* __restrict__ a_d,
                                                      const float* __restrict__ h,
                                                      const float* __restrict__ bias,
                                                      float* __restrict__ out, int N) {
    int n = blockIdx.x * 4 + (threadIdx.x >> 6);
    int lane = threadIdx.x & 63;
    if (n >= N) return;
    const int start = row_ptr[n];
    const int end = row_ptr[n + 1];
    const float adn = a_d[n];

    float m = -1e30f;
    for (int i = start + lane; i < end; i += 64) {
        float v = a_s[srcs[i]] + adn;
        v = (v >= 0.f) ? v : NEG_SLOPE * v;
        m = fmaxf(m, v);
    }
    m = wave_reduce_max(m);

    float l = 0.f;
    for (int i = start + lane; i < end; i += 64) {
        float v = a_s[srcs[i]] + adn;
        v = (v >= 0.f) ? v : NEG_SLOPE * v;
        l += __expf(v - m);
    }
    l = wave_reduce_sum(l);
    const float inv_den = 1.f / l;

    float acc = 0.f;
    for (int c = start; c < end; c += 64) {
        int cl = end - c;
        if (cl > 64) cl = 64;
        int sl = 0;
        float wl = 0.f;
        if (c + lane < end) {
            sl = srcs[c + lane];
            float v = a_s[sl] + adn;
            v = (v >= 0.f) ? v : NEG_SLOPE * v;
            wl = __expf(v - m) * inv_den;
        }
        for (int j = 0; j < cl; ++j) {
            float wj = __shfl(wl, j, 64);
            int sj = __shfl(sl, j, 64);
            acc += wj * h[(size_t)sj * 64 + lane];
        }
    }
    float o = acc + bias[lane];
    out[(size_t)n * 64 + lane] = o > 0.f ? o : 0.f;
}

// ---- graph boundaries: batch is sorted; gstart[g] = lower_bound(batch, g) ----
__global__ __launch_bounds__(256) void graph_bounds(const int* __restrict__ batch,
                                                    int* __restrict__ gstart, int N) {
    int g = blockIdx.x * 256 + threadIdx.x;
    if (g > NGRAPHS) return;
    int lo = 0, hi = N;
    while (lo < hi) {
        int mid = (lo + hi) >> 1;
        if (batch[mid] < g) lo = mid + 1; else hi = mid;
    }
    gstart[g] = lo;
}

// ---- fused mean-pool + final linear: one block (4 waves) per graph ----
__global__ __launch_bounds__(256) void pool_final(const float* __restrict__ x,
                                                  const int* __restrict__ gstart,
                                                  const float* __restrict__ Wlin,
                                                  const float* __restrict__ blin,
                                                  float* __restrict__ out) {
    __shared__ float red[4][64];
    const int g = blockIdx.x;
    const int lane = threadIdx.x & 63, w = threadIdx.x >> 6;
    const int s = gstart[g], e = gstart[g + 1];
    float acc = 0.f;
    for (int n = s + w; n < e; n += 4) acc += x[(size_t)n * 64 + lane];
    red[w][lane] = acc;
    __syncthreads();
    if (w == 0) {
        float p = red[0][lane] + red[1][lane] + red[2][lane] + red[3][lane];
        int c = e - s;
        p /= (float)(c > 1 ? c : 1);
        float o0 = wave_reduce_sum(p * Wlin[lane * 2 + 0]);
        float o1 = wave_reduce_sum(p * Wlin[lane * 2 + 1]);
        if (lane == 0) {
            out[g * 2 + 0] = o0 + blin[0];
            out[g * 2 + 1] = o1 + blin[1];
        }
    }
}

extern "C" void kernel_launch(void* const* d_in, const int* in_sizes, int n_in,
                              void* d_out, int out_size, void* d_ws, size_t ws_size,
                              hipStream_t stream) {
    const float* x    = (const float*)d_in[0];
    const int*   ei   = (const int*)d_in[1];
    const int*   batch= (const int*)d_in[2];
    const float* W1   = (const float*)d_in[3];
    const float* as1  = (const float*)d_in[4];
    const float* ad1  = (const float*)d_in[5];
    const float* b1   = (const float*)d_in[6];
    const float* W2   = (const float*)d_in[7];
    const float* as2  = (const float*)d_in[8];
    const float* ad2  = (const float*)d_in[9];
    const float* b2   = (const float*)d_in[10];
    const float* Wlin = (const float*)d_in[11];
    const float* blin = (const float*)d_in[12];
    float* out = (float*)d_out;

    const int FIN = 768;
    const int N  = in_sizes[0] / FIN;   // 50000
    const int E  = in_sizes[1] / 2;     // 800000
    const int ET = E + N;
    const size_t N64 = (size_t)N * 64;
    const int NB = 64;                  // scan blocks
    const int CH = (N + NB - 1) / NB;

    float* ws     = (float*)d_ws;
    float* hbuf   = ws;                          // N*64
    float* x1     = hbuf + N64;                  // N*64
    float* x2     = x1 + N64;                    // N*64
    float* a_s    = x2 + N64;                    // N
    float* a_d    = a_s + N;                     // N
    int* counts   = (int*)(a_d + N);             // N   (zeroed)
    int* row_ptr  = counts + N;                  // N+1
    int* next     = row_ptr + N + 1;             // N
    int* blk_sum  = next + N;                    // 64
    int* gstart   = blk_sum + 64;                // NGRAPHS+1
    int* srcs     = gstart + NGRAPHS + 1;        // ET
    uintptr_t wtp = (uintptr_t)(srcs + ET);
    wtp = (wtp + 15) & ~(uintptr_t)15;
    unsigned short* Wt1 = (unsigned short*)wtp;          // 64*768
    unsigned short* Wt2 = Wt1 + (size_t)64 * FIN;        // 64*64

    const int nEdgeBlk  = (ET + 255) / 256;
    const int nWaveBlkN = (N + 3) / 4;
    const int nGemmBlk  = (N + 63) / 64;

    hipMemsetAsync(counts, 0, (size_t)N * sizeof(int), stream);

    // ---- weight convert + graph bounds (tiny) ----
    convert_w<<<64, 256, 0, stream>>>(W1, Wt1, FIN);
    convert_w<<<64, 256, 0, stream>>>(W2, Wt2, 64);
    graph_bounds<<<(NGRAPHS + 256) / 256, 256, 0, stream>>>(batch, gstart, N);

    // ---- CSR build (by destination), reused by both layers ----
    hist_kernel<<<nEdgeBlk, 256, 0, stream>>>(ei, E, ET, counts);
    scan_sum<<<NB, 256, 0, stream>>>(counts, blk_sum, N, CH);
    scan_blk<<<1, 64, 0, stream>>>(blk_sum, row_ptr, N, NB);
    scan_local<<<NB, 256, 0, stream>>>(counts, blk_sum, row_ptr, next, N, CH);
    fill_kernel<<<nEdgeBlk, 256, 0, stream>>>(ei, E, ET, next, srcs);

    // ---- Layer 1: bf16 MFMA gemm + fused att ----
    gemm_att_mfma<<<nGemmBlk, 256, 0, stream>>>(x, Wt1, N, FIN, hbuf, as1, ad1,
                                                a_s, a_d);
    gat_agg_kernel<<<nWaveBlkN, 256, 0, stream>>>(row_ptr, srcs, a_s, a_d, hbuf,
                                                  b1, x1, N);

    // ---- Layer 2: fp32 gemm (K=64) + fused att ----
    gemm64s<<<nGemmBlk, 256, 0, stream>>>(x1, W2, hbuf, N, 64, as2, ad2, a_s, a_d);
    gat_agg_kernel<<<nWaveBlkN, 256, 0, stream>>>(row_ptr, srcs, a_s, a_d, hbuf,
                                                  b2, x2, N);

    // ---- Pool + final linear (fused, no atomics) ----
    pool_final<<<NGRAPHS, 256, 0, stream>>>(x2, gstart, Wlin, blin, out);
}

// Round 6
// 468.530 us; speedup vs baseline: 2.0996x; 1.1537x over previous
//
#include <hip/hip_runtime.h>

#define NEG_SLOPE 0.2f
#define NGRAPHS 512

typedef short short8 __attribute__((ext_vector_type(8)));
typedef float f32x4 __attribute__((ext_vector_type(4)));

__device__ __forceinline__ float wave_reduce_sum(float v) {
#pragma unroll
    for (int off = 32; off > 0; off >>= 1) v += __shfl_xor(v, off, 64);
    return v;
}
__device__ __forceinline__ float wave_reduce_max(float v) {
#pragma unroll
    for (int off = 32; off > 0; off >>= 1) v = fmaxf(v, __shfl_xor(v, off, 64));
    return v;
}
__device__ __forceinline__ unsigned short f2bf(float f) {  // fp32 -> bf16 RNE
    unsigned u = __float_as_uint(f);
    u += 0x7FFFu + ((u >> 16) & 1u);
    return (unsigned short)(u >> 16);
}

// W[K][64] fp32 -> Wt[64][K] bf16 (transposed). One block per output col n.
__global__ __launch_bounds__(256) void convert_w(const float* __restrict__ W,
                                                 unsigned short* __restrict__ Wt,
                                                 int K) {
    int n = blockIdx.x;
    for (int k = threadIdx.x; k < K; k += 256)
        Wt[(size_t)n * K + k] = f2bf(W[(size_t)k * 64 + n]);
}

// h[M,64] = A[M,K](fp32->bf16) @ Wt^T (Wt is [64][K] bf16), MFMA 16x16x32.
// Fused epilogue: a_s[r] = h[r,:]·att_s ; a_d[r] = h[r,:]·att_d.
__global__ __launch_bounds__(256) void gemm_att_mfma(
    const float* __restrict__ A, const unsigned short* __restrict__ Wt, int M, int K,
    float* __restrict__ h, const float* __restrict__ att_s,
    const float* __restrict__ att_d, float* __restrict__ a_s,
    float* __restrict__ a_d) {
    __shared__ unsigned short As[64][72];  // +8 pad: conflict-free b128 frag reads
    const int tid = threadIdx.x;
    const int w = tid >> 6, l = tid & 63, m = l & 15, q = l >> 4;
    const int row0 = blockIdx.x * 64;
    f32x4 acc0 = {0.f, 0.f, 0.f, 0.f}, acc1 = acc0, acc2 = acc0, acc3 = acc0;
    const int sr = tid >> 2, sc = tid & 3;  // staging: row 0..63, 16-elem k-chunk 0..3
    const int grow = row0 + sr;
    const bool rok = grow < M;
    if (!rok) {
#pragma unroll
        for (int j = 0; j < 16; ++j) As[sr][sc * 16 + j] = 0;
    }
    const float* Ap = A + (size_t)grow * K + sc * 16;

    for (int k0 = 0; k0 < K; k0 += 64) {
        if (rok) {
            const float4* p = (const float4*)(Ap + k0);
            float4 f0 = p[0], f1 = p[1], f2 = p[2], f3 = p[3];
            unsigned short t[16] = {
                f2bf(f0.x), f2bf(f0.y), f2bf(f0.z), f2bf(f0.w),
                f2bf(f1.x), f2bf(f1.y), f2bf(f1.z), f2bf(f1.w),
                f2bf(f2.x), f2bf(f2.y), f2bf(f2.z), f2bf(f2.w),
                f2bf(f3.x), f2bf(f3.y), f2bf(f3.z), f2bf(f3.w)};
            *(uint4*)&As[sr][sc * 16] = *(uint4*)&t[0];
            *(uint4*)&As[sr][sc * 16 + 8] = *(uint4*)&t[8];
        }
        __syncthreads();
        const unsigned short* arow = &As[w * 16 + m][0];
        const unsigned short* brow = Wt + (size_t)m * K + k0;
#pragma unroll
        for (int kk = 0; kk < 2; ++kk) {
            short8 av = *(const short8*)(arow + kk * 32 + q * 8);
            const unsigned short* bp = brow + kk * 32 + q * 8;
            acc0 = __builtin_amdgcn_mfma_f32_16x16x32_bf16(
                av, *(const short8*)(bp), acc0, 0, 0, 0);
            acc1 = __builtin_amdgcn_mfma_f32_16x16x32_bf16(
                av, *(const short8*)(bp + (size_t)16 * K), acc1, 0, 0, 0);
            acc2 = __builtin_amdgcn_mfma_f32_16x16x32_bf16(
                av, *(const short8*)(bp + (size_t)32 * K), acc2, 0, 0, 0);
            acc3 = __builtin_amdgcn_mfma_f32_16x16x32_bf16(
                av, *(const short8*)(bp + (size_t)48 * K), acc3, 0, 0, 0);
        }
        __syncthreads();
    }
    // epilogue: C/D layout col=lane&15, row=q*4+reg (per 16-col group)
    float as0 = att_s[m], as1 = att_s[16 + m], as2 = att_s[32 + m], as3 = att_s[48 + m];
    float ad0 = att_d[m], ad1 = att_d[16 + m], ad2 = att_d[32 + m], ad3 = att_d[48 + m];
    const int rowb = row0 + w * 16 + q * 4;
#pragma unroll
    for (int r = 0; r < 4; ++r) {
        int row = rowb + r;
        float v0 = acc0[r], v1 = acc1[r], v2 = acc2[r], v3 = acc3[r];
        if (row < M) {
            float* hp = h + (size_t)row * 64 + m;
            hp[0] = v0; hp[16] = v1; hp[32] = v2; hp[48] = v3;
        }
        float hs = v0 * as0 + v1 * as1 + v2 * as2 + v3 * as3;
        float hd = v0 * ad0 + v1 * ad1 + v2 * ad2 + v3 * ad3;
#pragma unroll
        for (int off = 1; off < 16; off <<= 1) {
            hs += __shfl_xor(hs, off, 64);
            hd += __shfl_xor(hd, off, 64);
        }
        if (m == 0 && row < M) { a_s[row] = hs; a_d[row] = hd; }
    }
}

// fp32 GEMM (layer 2, K=64) with fused att epilogue. As k-major (conflict-free).
__global__ __launch_bounds__(256) void gemm64s(const float* __restrict__ A,
                                               const float* __restrict__ B,
                                               float* __restrict__ C, int M, int K,
                                               const float* __restrict__ att_s,
                                               const float* __restrict__ att_d,
                                               float* __restrict__ a_s,
                                               float* __restrict__ a_d) {
    __shared__ float As[16][64];
    __shared__ float Bs[16][64];
    const int tid = threadIdx.x;
    const int tx = tid & 15;
    const int ty = tid >> 4;
    const int row0 = blockIdx.x * 64;
    float acc[4][4] = {};
    const int la_row = tid >> 2;
    const int la_col = (tid & 3) * 4;
    const int lb_row = tid >> 4;
    const int lb_col = (tid & 15) * 4;

    for (int k0 = 0; k0 < K; k0 += 16) {
        int ar = row0 + la_row;
        float4 av = make_float4(0.f, 0.f, 0.f, 0.f);
        if (ar < M) av = *(const float4*)(A + (size_t)ar * K + k0 + la_col);
        As[la_col + 0][la_row] = av.x;
        As[la_col + 1][la_row] = av.y;
        As[la_col + 2][la_row] = av.z;
        As[la_col + 3][la_row] = av.w;
        *(float4*)&Bs[lb_row][lb_col] =
            *(const float4*)(B + (size_t)(k0 + lb_row) * 64 + lb_col);
        __syncthreads();
#pragma unroll
        for (int k = 0; k < 16; ++k) {
            float4 a4 = *(float4*)&As[k][ty * 4];
            float4 b4 = *(float4*)&Bs[k][tx * 4];
            acc[0][0] += a4.x * b4.x; acc[0][1] += a4.x * b4.y;
            acc[0][2] += a4.x * b4.z; acc[0][3] += a4.x * b4.w;
            acc[1][0] += a4.y * b4.x; acc[1][1] += a4.y * b4.y;
            acc[1][2] += a4.y * b4.z; acc[1][3] += a4.y * b4.w;
            acc[2][0] += a4.z * b4.x; acc[2][1] += a4.z * b4.y;
            acc[2][2] += a4.z * b4.z; acc[2][3] += a4.z * b4.w;
            acc[3][0] += a4.w * b4.x; acc[3][1] += a4.w * b4.y;
            acc[3][2] += a4.w * b4.z; acc[3][3] += a4.w * b4.w;
        }
        __syncthreads();
    }
    float asv[4], adv[4];
#pragma unroll
    for (int j = 0; j < 4; ++j) {
        asv[j] = att_s[tx * 4 + j];
        adv[j] = att_d[tx * 4 + j];
    }
#pragma unroll
    for (int i = 0; i < 4; ++i) {
        int row = row0 + ty * 4 + i;
        if (row < M) {
            float4 v = make_float4(acc[i][0], acc[i][1], acc[i][2], acc[i][3]);
            *(float4*)(C + (size_t)row * 64 + tx * 4) = v;
        }
        float hs = acc[i][0] * asv[0] + acc[i][1] * asv[1] +
                   acc[i][2] * asv[2] + acc[i][3] * asv[3];
        float hd = acc[i][0] * adv[0] + acc[i][1] * adv[1] +
                   acc[i][2] * adv[2] + acc[i][3] * adv[3];
#pragma unroll
        for (int off = 1; off < 16; off <<= 1) {
            hs += __shfl_xor(hs, off, 64);
            hd += __shfl_xor(hd, off, 64);
        }
        if (tx == 0 && row < M) { a_s[row] = hs; a_d[row] = hd; }
    }
}

__device__ __forceinline__ void edge_sd(const int* __restrict__ ei, int E, int e,
                                        int& s, int& d) {
    if (e < E) { s = ei[e]; d = ei[E + e]; }
    else { s = d = e - E; }
}

// ---- CSR build ----
__global__ __launch_bounds__(256) void hist_kernel(const int* __restrict__ ei, int E,
                                                   int ET, int* __restrict__ counts) {
    int e = blockIdx.x * 256 + threadIdx.x;
    if (e >= ET) return;
    int s, d;
    edge_sd(ei, E, e, s, d);
    atomicAdd(counts + d, 1);
}

// per-block sums over chunks of CH
__global__ __launch_bounds__(256) void scan_sum(const int* __restrict__ counts,
                                                int* __restrict__ blk_sum, int N,
                                                int CH) {
    __shared__ int wsum[4];
    const int tid = threadIdx.x, lane = tid & 63, wid = tid >> 6;
    const int b = blockIdx.x;
    int begin = b * CH, endi = min(begin + CH, N);
    int s = 0;
    for (int i = begin + tid; i < endi; i += 256) s += counts[i];
#pragma unroll
    for (int off = 32; off > 0; off >>= 1) s += __shfl_xor(s, off, 64);
    if (lane == 0) wsum[wid] = s;
    __syncthreads();
    if (tid == 0) blk_sum[b] = wsum[0] + wsum[1] + wsum[2] + wsum[3];
}

// exclusive scan of 64 block sums (1 wave); also writes row_ptr[N]=total
__global__ __launch_bounds__(64) void scan_blk(int* __restrict__ blk_sum,
                                               int* __restrict__ row_ptr, int N,
                                               int nb) {
    int t = threadIdx.x;
    int v = (t < nb) ? blk_sum[t] : 0;
    int sv = v;
#pragma unroll
    for (int off = 1; off < 64; off <<= 1) {
        int u = __shfl_up(sv, off, 64);
        if (t >= off) sv += u;
    }
    if (t < nb) blk_sum[t] = sv - v;
    if (t == nb - 1) row_ptr[N] = sv;
}

// local exclusive scan with block offset; writes row_ptr AND next
__global__ __launch_bounds__(256) void scan_local(const int* __restrict__ counts,
                                                  const int* __restrict__ blk_off,
                                                  int* __restrict__ row_ptr,
                                                  int* __restrict__ next_, int N,
                                                  int CH) {
    __shared__ int wsum[4];
    __shared__ int ctot;
    const int tid = threadIdx.x, lane = tid & 63, wid = tid >> 6;
    const int b = blockIdx.x;
    int begin = b * CH, endi = min(begin + CH, N);
    int carry = blk_off[b];
    for (int base = begin; base < endi; base += 256) {
        int i = base + tid;
        int v = (i < endi) ? counts[i] : 0;
        int sv = v;
#pragma unroll
        for (int off = 1; off < 64; off <<= 1) {
            int u = __shfl_up(sv, off, 64);
            if (lane >= off) sv += u;
        }
        if (lane == 63) wsum[wid] = sv;
        __syncthreads();
        if (tid == 0) {
            int a = 0;
#pragma unroll
            for (int j = 0; j < 4; ++j) { int u = wsum[j]; wsum[j] = a; a += u; }
            ctot = a;
        }
        __syncthreads();
        int excl = carry + wsum[wid] + sv - v;
        if (i < endi) { row_ptr[i] = excl; next_[i] = excl; }
        carry += ctot;
        __syncthreads();
    }
}

__global__ __launch_bounds__(256) void fill_kernel(const int* __restrict__ ei, int E,
                                                   int ET, int* __restrict__ next,
                                                   int* __restrict__ srcs) {
    int e = blockIdx.x * 256 + threadIdx.x;
    if (e >= ET) return;
    int s, d;
    edge_sd(ei, E, e, s, d);
    int pos = atomicAdd(next + d, 1);
    srcs[pos] = s;
}

// ---- fused edge-softmax + aggregation + bias + relu: one wave per dst node ----
// Fast path (deg<=64): single pass over srcs/a_s kept in registers; aggregation
// processes 4 edges/step (lane = 16*edge_quad + feature_quad, float4 h loads).
__global__ __launch_bounds__(256) void gat_agg_kernel(const int* __restrict__ row_ptr,
                                                      const int* __restrict__ srcs,
                                                      const float* __restrict__ a_s,
                                                      const float* __restrict__ a_d,
                                                      const float* __restrict__ h,
                                                      const float* __restrict__ bias,
                                                      float* __restrict__ out, int N) {
    int n = blockIdx.x * 4 + (threadIdx.x >> 6);
    int lane = threadIdx.x & 63;
    if (n >= N) return;
    const int start = row_ptr[n];
    const int deg = row_ptr[n + 1] - start;
    const float adn = a_d[n];

    if (deg <= 64) {
        int sl = 0;
        float v = -1e30f;
        if (lane < deg) {
            sl = srcs[start + lane];
            float t = a_s[sl] + adn;
            v = (t >= 0.f) ? t : NEG_SLOPE * t;
        }
        float m = wave_reduce_max(v);
        float wl = (lane < deg) ? __expf(v - m) : 0.f;
        float l = wave_reduce_sum(wl);
        wl *= (1.f / l);

        const int eq = lane >> 4, fq = lane & 15;
        float ax = 0.f, ay = 0.f, az = 0.f, aw = 0.f;
        for (int j = 0; j < deg; j += 4) {
            int idx = j + eq;
            bool ok = idx < deg;
            int ii = ok ? idx : 0;
            float a = __shfl(wl, ii, 64);
            int s = __shfl(sl, ii, 64);
            if (!ok) a = 0.f;
            const float4 hv = *(const float4*)(h + (size_t)s * 64 + fq * 4);
            ax += a * hv.x; ay += a * hv.y; az += a * hv.z; aw += a * hv.w;
        }
#pragma unroll
        for (int off = 16; off <= 32; off <<= 1) {
            ax += __shfl_xor(ax, off, 64);
            ay += __shfl_xor(ay, off, 64);
            az += __shfl_xor(az, off, 64);
            aw += __shfl_xor(aw, off, 64);
        }
        if (eq == 0) {
            const float4 bv = *(const float4*)(bias + fq * 4);
            float4 o;
            o.x = ax + bv.x; o.y = ay + bv.y; o.z = az + bv.z; o.w = aw + bv.w;
            o.x = o.x > 0.f ? o.x : 0.f;
            o.y = o.y > 0.f ? o.y : 0.f;
            o.z = o.z > 0.f ? o.z : 0.f;
            o.w = o.w > 0.f ? o.w : 0.f;
            *(float4*)(out + (size_t)n * 64 + fq * 4) = o;
        }
        return;
    }

    // general path (deg > 64) — statistically absent for this graph
    const int end = start + deg;
    float m = -1e30f;
    for (int i = start + lane; i < end; i += 64) {
        float v = a_s[srcs[i]] + adn;
        v = (v >= 0.f) ? v : NEG_SLOPE * v;
        m = fmaxf(m, v);
    }
    m = wave_reduce_max(m);
    float l = 0.f;
    for (int i = start + lane; i < end; i += 64) {
        float v = a_s[srcs[i]] + adn;
        v = (v >= 0.f) ? v : NEG_SLOPE * v;
        l += __expf(v - m);
    }
    l = wave_reduce_sum(l);
    const float inv_den = 1.f / l;
    float acc = 0.f;
    for (int c = start; c < end; c += 64) {
        int cl = end - c;
        if (cl > 64) cl = 64;
        int sl = 0;
        float wl = 0.f;
        if (c + lane < end) {
            sl = srcs[c + lane];
            float v = a_s[sl] + adn;
            v = (v >= 0.f) ? v : NEG_SLOPE * v;
            wl = __expf(v - m) * inv_den;
        }
        for (int j = 0; j < cl; ++j) {
            float wj = __shfl(wl, j, 64);
            int sj = __shfl(sl, j, 64);
            acc += wj * h[(size_t)sj * 64 + lane];
        }
    }
    float o = acc + bias[lane];
    out[(size_t)n * 64 + lane] = o > 0.f ? o : 0.f;
}

// ---- graph boundaries: batch is sorted; gstart[g] = lower_bound(batch, g) ----
__global__ __launch_bounds__(256) void graph_bounds(const int* __restrict__ batch,
                                                    int* __restrict__ gstart, int N) {
    int g = blockIdx.x * 256 + threadIdx.x;
    if (g > NGRAPHS) return;
    int lo = 0, hi = N;
    while (lo < hi) {
        int mid = (lo + hi) >> 1;
        if (batch[mid] < g) lo = mid + 1; else hi = mid;
    }
    gstart[g] = lo;
}

// ---- fused mean-pool + final linear: one block (4 waves) per graph ----
__global__ __launch_bounds__(256) void pool_final(const float* __restrict__ x,
                                                  const int* __restrict__ gstart,
                                                  const float* __restrict__ Wlin,
                                                  const float* __restrict__ blin,
                                                  float* __restrict__ out) {
    __shared__ float red[4][64];
    const int g = blockIdx.x;
    const int lane = threadIdx.x & 63, w = threadIdx.x >> 6;
    const int s = gstart[g], e = gstart[g + 1];
    float acc = 0.f;
    for (int n = s + w; n < e; n += 4) acc += x[(size_t)n * 64 + lane];
    red[w][lane] = acc;
    __syncthreads();
    if (w == 0) {
        float p = red[0][lane] + red[1][lane] + red[2][lane] + red[3][lane];
        int c = e - s;
        p /= (float)(c > 1 ? c : 1);
        float o0 = wave_reduce_sum(p * Wlin[lane * 2 + 0]);
        float o1 = wave_reduce_sum(p * Wlin[lane * 2 + 1]);
        if (lane == 0) {
            out[g * 2 + 0] = o0 + blin[0];
            out[g * 2 + 1] = o1 + blin[1];
        }
    }
}

extern "C" void kernel_launch(void* const* d_in, const int* in_sizes, int n_in,
                              void* d_out, int out_size, void* d_ws, size_t ws_size,
                              hipStream_t stream) {
    const float* x    = (const float*)d_in[0];
    const int*   ei   = (const int*)d_in[1];
    const int*   batch= (const int*)d_in[2];
    const float* W1   = (const float*)d_in[3];
    const float* as1  = (const float*)d_in[4];
    const float* ad1  = (const float*)d_in[5];
    const float* b1   = (const float*)d_in[6];
    const float* W2   = (const float*)d_in[7];
    const float* as2  = (const float*)d_in[8];
    const float* ad2  = (const float*)d_in[9];
    const float* b2   = (const float*)d_in[10];
    const float* Wlin = (const float*)d_in[11];
    const float* blin = (const float*)d_in[12];
    float* out = (float*)d_out;

    const int FIN = 768;
    const int N  = in_sizes[0] / FIN;   // 50000
    const int E  = in_sizes[1] / 2;     // 800000
    const int ET = E + N;
    const size_t N64 = (size_t)N * 64;
    const int NB = 64;                  // scan blocks
    const int CH = (N + NB - 1) / NB;

    float* ws     = (float*)d_ws;
    float* hbuf   = ws;                          // N*64
    float* x1     = hbuf + N64;                  // N*64
    float* x2     = x1 + N64;                    // N*64
    float* a_s    = x2 + N64;                    // N
    float* a_d    = a_s + N;                     // N
    int* counts   = (int*)(a_d + N);             // N   (zeroed)
    int* row_ptr  = counts + N;                  // N+1
    int* next     = row_ptr + N + 1;             // N
    int* blk_sum  = next + N;                    // 64
    int* gstart   = blk_sum + 64;                // NGRAPHS+1
    int* srcs     = gstart + NGRAPHS + 1;        // ET
    uintptr_t wtp = (uintptr_t)(srcs + ET);
    wtp = (wtp + 15) & ~(uintptr_t)15;
    unsigned short* Wt1 = (unsigned short*)wtp;          // 64*768
    unsigned short* Wt2 = Wt1 + (size_t)64 * FIN;        // 64*64

    const int nEdgeBlk  = (ET + 255) / 256;
    const int nWaveBlkN = (N + 3) / 4;
    const int nGemmBlk  = (N + 63) / 64;

    hipMemsetAsync(counts, 0, (size_t)N * sizeof(int), stream);

    // ---- weight convert + graph bounds (tiny) ----
    convert_w<<<64, 256, 0, stream>>>(W1, Wt1, FIN);
    convert_w<<<64, 256, 0, stream>>>(W2, Wt2, 64);
    graph_bounds<<<(NGRAPHS + 256) / 256, 256, 0, stream>>>(batch, gstart, N);

    // ---- CSR build (by destination), reused by both layers ----
    hist_kernel<<<nEdgeBlk, 256, 0, stream>>>(ei, E, ET, counts);
    scan_sum<<<NB, 256, 0, stream>>>(counts, blk_sum, N, CH);
    scan_blk<<<1, 64, 0, stream>>>(blk_sum, row_ptr, N, NB);
    scan_local<<<NB, 256, 0, stream>>>(counts, blk_sum, row_ptr, next, N, CH);
    fill_kernel<<<nEdgeBlk, 256, 0, stream>>>(ei, E, ET, next, srcs);

    // ---- Layer 1: bf16 MFMA gemm + fused att ----
    gemm_att_mfma<<<nGemmBlk, 256, 0, stream>>>(x, Wt1, N, FIN, hbuf, as1, ad1,
                                                a_s, a_d);
    gat_agg_kernel<<<nWaveBlkN, 256, 0, stream>>>(row_ptr, srcs, a_s, a_d, hbuf,
                                                  b1, x1, N);

    // ---- Layer 2: fp32 gemm (K=64) + fused att ----
    gemm64s<<<nGemmBlk, 256, 0, stream>>>(x1, W2, hbuf, N, 64, as2, ad2, a_s, a_d);
    gat_agg_kernel<<<nWaveBlkN, 256, 0, stream>>>(row_ptr, srcs, a_s, a_d, hbuf,
                                                  b2, x2, N);

    // ---- Pool + final linear (fused, no atomics) ----
    pool_final<<<NGRAPHS, 256, 0, stream>>>(x2, gstart, Wlin, blin, out);
}

// Round 7
// 444.024 us; speedup vs baseline: 2.2155x; 1.0552x over previous
//
#include <hip/hip_runtime.h>

#define NEG_SLOPE 0.2f
#define NGRAPHS 512

typedef short short8 __attribute__((ext_vector_type(8)));
typedef float f32x4 __attribute__((ext_vector_type(4)));

__device__ __forceinline__ float wave_reduce_sum(float v) {
#pragma unroll
    for (int off = 32; off > 0; off >>= 1) v += __shfl_xor(v, off, 64);
    return v;
}
__device__ __forceinline__ float wave_reduce_max(float v) {
#pragma unroll
    for (int off = 32; off > 0; off >>= 1) v = fmaxf(v, __shfl_xor(v, off, 64));
    return v;
}
__device__ __forceinline__ unsigned short f2bf(float f) {  // fp32 -> bf16 RNE
    unsigned u = __float_as_uint(f);
    u += 0x7FFFu + ((u >> 16) & 1u);
    return (unsigned short)(u >> 16);
}

__device__ __forceinline__ void edge_sd(const int* __restrict__ ei, int E, int e,
                                        int& s, int& d) {
    if (e < E) { s = ei[e]; d = ei[E + e]; }
    else { s = d = e - E; }  // appended self-loops
}

// ---- setup + histogram, block-specialized:
// blocks [0,nEdgeBlk): hist; [+64): convert W1; [+1): convert W2; [+1): bounds
__global__ __launch_bounds__(256) void setup_hist(
    const int* __restrict__ ei, int E, int ET, int* __restrict__ counts,
    int nEdgeBlk, const float* __restrict__ W1, unsigned short* __restrict__ Wt1,
    int K1, const float* __restrict__ W2, unsigned short* __restrict__ Wt2,
    const int* __restrict__ batch, int* __restrict__ gstart, int N) {
    const int b = blockIdx.x, tid = threadIdx.x;
    if (b < nEdgeBlk) {
        int e = b * 256 + tid;
        if (e >= ET) return;
        int s, d;
        edge_sd(ei, E, e, s, d);
        atomicAdd(counts + d, 1);
    } else if (b < nEdgeBlk + 64) {
        int n = b - nEdgeBlk;
        for (int k = tid; k < K1; k += 256)
            Wt1[(size_t)n * K1 + k] = f2bf(W1[(size_t)k * 64 + n]);
    } else if (b == nEdgeBlk + 64) {
#pragma unroll
        for (int i = 0; i < 16; ++i) {
            int idx = tid + i * 256;
            int n = idx >> 6, k = idx & 63;
            Wt2[n * 64 + k] = f2bf(W2[k * 64 + n]);
        }
    } else {
        for (int g = tid; g <= NGRAPHS; g += 256) {
            int lo = 0, hi = N;
            while (lo < hi) {
                int mid = (lo + hi) >> 1;
                if (batch[mid] < g) lo = mid + 1; else hi = mid;
            }
            gstart[g] = lo;
        }
    }
}

// per-block sums over chunks of CH
__global__ __launch_bounds__(256) void scan_sum(const int* __restrict__ counts,
                                                int* __restrict__ blk_sum, int N,
                                                int CH) {
    __shared__ int wsum[4];
    const int tid = threadIdx.x, lane = tid & 63, wid = tid >> 6;
    const int b = blockIdx.x;
    int begin = b * CH, endi = min(begin + CH, N);
    int s = 0;
    for (int i = begin + tid; i < endi; i += 256) s += counts[i];
#pragma unroll
    for (int off = 32; off > 0; off >>= 1) s += __shfl_xor(s, off, 64);
    if (lane == 0) wsum[wid] = s;
    __syncthreads();
    if (tid == 0) blk_sum[b] = wsum[0] + wsum[1] + wsum[2] + wsum[3];
}

// exclusive scan of 64 block sums (1 wave); also writes row_ptr[N]=total
__global__ __launch_bounds__(64) void scan_blk(int* __restrict__ blk_sum,
                                               int* __restrict__ row_ptr, int N,
                                               int nb) {
    int t = threadIdx.x;
    int v = (t < nb) ? blk_sum[t] : 0;
    int sv = v;
#pragma unroll
    for (int off = 1; off < 64; off <<= 1) {
        int u = __shfl_up(sv, off, 64);
        if (t >= off) sv += u;
    }
    if (t < nb) blk_sum[t] = sv - v;
    if (t == nb - 1) row_ptr[N] = sv;
}

// local exclusive scan with block offset; writes row_ptr AND next
__global__ __launch_bounds__(256) void scan_local(const int* __restrict__ counts,
                                                  const int* __restrict__ blk_off,
                                                  int* __restrict__ row_ptr,
                                                  int* __restrict__ next_, int N,
                                                  int CH) {
    __shared__ int wsum[4];
    __shared__ int ctot;
    const int tid = threadIdx.x, lane = tid & 63, wid = tid >> 6;
    const int b = blockIdx.x;
    int begin = b * CH, endi = min(begin + CH, N);
    int carry = blk_off[b];
    for (int base = begin; base < endi; base += 256) {
        int i = base + tid;
        int v = (i < endi) ? counts[i] : 0;
        int sv = v;
#pragma unroll
        for (int off = 1; off < 64; off <<= 1) {
            int u = __shfl_up(sv, off, 64);
            if (lane >= off) sv += u;
        }
        if (lane == 63) wsum[wid] = sv;
        __syncthreads();
        if (tid == 0) {
            int a = 0;
#pragma unroll
            for (int j = 0; j < 4; ++j) { int u = wsum[j]; wsum[j] = a; a += u; }
            ctot = a;
        }
        __syncthreads();
        int excl = carry + wsum[wid] + sv - v;
        if (i < endi) { row_ptr[i] = excl; next_[i] = excl; }
        carry += ctot;
        __syncthreads();
    }
}

// ---- Layer-1 GEMM (bf16 MFMA, K-chunk=256) + fused att epilogue, with CSR
// fill fused in as extra blocks (they ignore the LDS).
__global__ __launch_bounds__(256) void gemm1_fill(
    const float* __restrict__ A, const unsigned short* __restrict__ Wt, int M, int K,
    float* __restrict__ h, const float* __restrict__ att_s,
    const float* __restrict__ att_d, float* __restrict__ a_s,
    float* __restrict__ a_d, int nGemm, const int* __restrict__ ei, int E, int ET,
    int* __restrict__ next_, int* __restrict__ srcs) {
    __shared__ unsigned short As[64][264];  // stride 264: 2-way (free) bank aliasing
    const int tid = threadIdx.x;
    if (blockIdx.x >= nGemm) {  // ---- fill part ----
        int e = (blockIdx.x - nGemm) * 256 + tid;
        if (e >= ET) return;
        int s, d;
        edge_sd(ei, E, e, s, d);
        int pos = atomicAdd(next_ + d, 1);
        srcs[pos] = s;
        return;
    }
    // ---- gemm part ----
    const int w = tid >> 6, l = tid & 63, m = l & 15, q = l >> 4;
    const int row0 = blockIdx.x * 64;
    f32x4 acc0 = {0.f, 0.f, 0.f, 0.f}, acc1 = acc0, acc2 = acc0, acc3 = acc0;
    const int sr = tid >> 2, sc = tid & 3;  // staging: row, 64-elem k-slice
    const int grow = row0 + sr;
    const bool rok = grow < M;
    if (!rok) {
#pragma unroll
        for (int u = 0; u < 8; ++u)
            *(uint4*)&As[sr][sc * 64 + u * 8] = make_uint4(0, 0, 0, 0);
    }
    const float* Ap = A + (size_t)grow * K + sc * 64;

    for (int c = 0; c < 3; ++c) {  // K=768 in 3 chunks of 256
        if (rok) {
            for (int u = 0; u < 4; ++u) {
                const float4* p = (const float4*)(Ap + c * 256 + u * 16);
                float4 f0 = p[0], f1 = p[1], f2 = p[2], f3 = p[3];
                unsigned short t[16] = {
                    f2bf(f0.x), f2bf(f0.y), f2bf(f0.z), f2bf(f0.w),
                    f2bf(f1.x), f2bf(f1.y), f2bf(f1.z), f2bf(f1.w),
                    f2bf(f2.x), f2bf(f2.y), f2bf(f2.z), f2bf(f2.w),
                    f2bf(f3.x), f2bf(f3.y), f2bf(f3.z), f2bf(f3.w)};
                *(uint4*)&As[sr][sc * 64 + u * 16] = *(uint4*)&t[0];
                *(uint4*)&As[sr][sc * 64 + u * 16 + 8] = *(uint4*)&t[8];
            }
        }
        __syncthreads();
        const unsigned short* arow = &As[w * 16 + m][0];
        const unsigned short* brow = Wt + (size_t)m * K + c * 256;
#pragma unroll
        for (int ks = 0; ks < 8; ++ks) {
            short8 av = *(const short8*)(arow + ks * 32 + q * 8);
            const unsigned short* bp = brow + ks * 32 + q * 8;
            acc0 = __builtin_amdgcn_mfma_f32_16x16x32_bf16(
                av, *(const short8*)(bp), acc0, 0, 0, 0);
            acc1 = __builtin_amdgcn_mfma_f32_16x16x32_bf16(
                av, *(const short8*)(bp + (size_t)16 * K), acc1, 0, 0, 0);
            acc2 = __builtin_amdgcn_mfma_f32_16x16x32_bf16(
                av, *(const short8*)(bp + (size_t)32 * K), acc2, 0, 0, 0);
            acc3 = __builtin_amdgcn_mfma_f32_16x16x32_bf16(
                av, *(const short8*)(bp + (size_t)48 * K), acc3, 0, 0, 0);
        }
        __syncthreads();
    }
    // epilogue: C/D layout col=lane&15, row=q*4+reg
    float as0 = att_s[m], as1 = att_s[16 + m], as2 = att_s[32 + m], as3 = att_s[48 + m];
    float ad0 = att_d[m], ad1 = att_d[16 + m], ad2 = att_d[32 + m], ad3 = att_d[48 + m];
    const int rowb = row0 + w * 16 + q * 4;
#pragma unroll
    for (int r = 0; r < 4; ++r) {
        int row = rowb + r;
        float v0 = acc0[r], v1 = acc1[r], v2 = acc2[r], v3 = acc3[r];
        if (row < M) {
            float* hp = h + (size_t)row * 64 + m;
            hp[0] = v0; hp[16] = v1; hp[32] = v2; hp[48] = v3;
        }
        float hs = v0 * as0 + v1 * as1 + v2 * as2 + v3 * as3;
        float hd = v0 * ad0 + v1 * ad1 + v2 * ad2 + v3 * ad3;
#pragma unroll
        for (int off = 1; off < 16; off <<= 1) {
            hs += __shfl_xor(hs, off, 64);
            hd += __shfl_xor(hd, off, 64);
        }
        if (m == 0 && row < M) { a_s[row] = hs; a_d[row] = hd; }
    }
}

// ---- Layer-2 GEMM: bf16 MFMA, K=64, no LDS (frags from L2) + fused att ----
__global__ __launch_bounds__(256) void gemm2_mfma(
    const unsigned short* __restrict__ Ab, const unsigned short* __restrict__ Wt2,
    int M, float* __restrict__ h, const float* __restrict__ att_s,
    const float* __restrict__ att_d, float* __restrict__ a_s,
    float* __restrict__ a_d) {
    const int tid = threadIdx.x;
    const int w = tid >> 6, l = tid & 63, m = l & 15, q = l >> 4;
    const int row0 = blockIdx.x * 64;
    const int r = row0 + w * 16 + m;  // A-frag row
    short8 av0 = {0, 0, 0, 0, 0, 0, 0, 0}, av1 = av0;
    if (r < M) {
        av0 = *(const short8*)(Ab + (size_t)r * 64 + q * 8);
        av1 = *(const short8*)(Ab + (size_t)r * 64 + 32 + q * 8);
    }
    f32x4 acc0 = {0.f, 0.f, 0.f, 0.f}, acc1 = acc0, acc2 = acc0, acc3 = acc0;
    const unsigned short* bp = Wt2 + (size_t)m * 64 + q * 8;
    acc0 = __builtin_amdgcn_mfma_f32_16x16x32_bf16(av0, *(const short8*)(bp), acc0, 0, 0, 0);
    acc0 = __builtin_amdgcn_mfma_f32_16x16x32_bf16(av1, *(const short8*)(bp + 32), acc0, 0, 0, 0);
    acc1 = __builtin_amdgcn_mfma_f32_16x16x32_bf16(av0, *(const short8*)(bp + 16 * 64), acc1, 0, 0, 0);
    acc1 = __builtin_amdgcn_mfma_f32_16x16x32_bf16(av1, *(const short8*)(bp + 16 * 64 + 32), acc1, 0, 0, 0);
    acc2 = __builtin_amdgcn_mfma_f32_16x16x32_bf16(av0, *(const short8*)(bp + 32 * 64), acc2, 0, 0, 0);
    acc2 = __builtin_amdgcn_mfma_f32_16x16x32_bf16(av1, *(const short8*)(bp + 32 * 64 + 32), acc2, 0, 0, 0);
    acc3 = __builtin_amdgcn_mfma_f32_16x16x32_bf16(av0, *(const short8*)(bp + 48 * 64), acc3, 0, 0, 0);
    acc3 = __builtin_amdgcn_mfma_f32_16x16x32_bf16(av1, *(const short8*)(bp + 48 * 64 + 32), acc3, 0, 0, 0);

    float as0 = att_s[m], as1 = att_s[16 + m], as2 = att_s[32 + m], as3 = att_s[48 + m];
    float ad0 = att_d[m], ad1 = att_d[16 + m], ad2 = att_d[32 + m], ad3 = att_d[48 + m];
    const int rowb = row0 + w * 16 + q * 4;
#pragma unroll
    for (int rr = 0; rr < 4; ++rr) {
        int row = rowb + rr;
        float v0 = acc0[rr], v1 = acc1[rr], v2 = acc2[rr], v3 = acc3[rr];
        if (row < M) {
            float* hp = h + (size_t)row * 64 + m;
            hp[0] = v0; hp[16] = v1; hp[32] = v2; hp[48] = v3;
        }
        float hs = v0 * as0 + v1 * as1 + v2 * as2 + v3 * as3;
        float hd = v0 * ad0 + v1 * ad1 + v2 * ad2 + v3 * ad3;
#pragma unroll
        for (int off = 1; off < 16; off <<= 1) {
            hs += __shfl_xor(hs, off, 64);
            hd += __shfl_xor(hd, off, 64);
        }
        if (m == 0 && row < M) { a_s[row] = hs; a_d[row] = hd; }
    }
}

// ---- fused edge-softmax + aggregation + bias + relu: one wave per dst node.
// out (fp32) and outb (bf16) are each optional.
__global__ __launch_bounds__(256) void gat_agg_kernel(
    const int* __restrict__ row_ptr, const int* __restrict__ srcs,
    const float* __restrict__ a_s, const float* __restrict__ a_d,
    const float* __restrict__ h, const float* __restrict__ bias,
    float* __restrict__ out, unsigned short* __restrict__ outb, int N) {
    int n = blockIdx.x * 4 + (threadIdx.x >> 6);
    int lane = threadIdx.x & 63;
    if (n >= N) return;
    const int start = row_ptr[n];
    const int deg = row_ptr[n + 1] - start;
    const float adn = a_d[n];

    if (deg <= 64) {
        int sl = 0;
        float v = -1e30f;
        if (lane < deg) {
            sl = srcs[start + lane];
            float t = a_s[sl] + adn;
            v = (t >= 0.f) ? t : NEG_SLOPE * t;
        }
        float m = wave_reduce_max(v);
        float wl = (lane < deg) ? __expf(v - m) : 0.f;
        float l = wave_reduce_sum(wl);
        wl *= (1.f / l);

        const int eq = lane >> 4, fq = lane & 15;
        float ax = 0.f, ay = 0.f, az = 0.f, aw = 0.f;
        for (int j = 0; j < deg; j += 4) {
            int idx = j + eq;
            bool ok = idx < deg;
            int ii = ok ? idx : 0;
            float a = __shfl(wl, ii, 64);
            int s = __shfl(sl, ii, 64);
            if (!ok) a = 0.f;
            const float4 hv = *(const float4*)(h + (size_t)s * 64 + fq * 4);
            ax += a * hv.x; ay += a * hv.y; az += a * hv.z; aw += a * hv.w;
        }
#pragma unroll
        for (int off = 16; off <= 32; off <<= 1) {
            ax += __shfl_xor(ax, off, 64);
            ay += __shfl_xor(ay, off, 64);
            az += __shfl_xor(az, off, 64);
            aw += __shfl_xor(aw, off, 64);
        }
        if (eq == 0) {
            const float4 bv = *(const float4*)(bias + fq * 4);
            float4 o;
            o.x = ax + bv.x; o.y = ay + bv.y; o.z = az + bv.z; o.w = aw + bv.w;
            o.x = o.x > 0.f ? o.x : 0.f;
            o.y = o.y > 0.f ? o.y : 0.f;
            o.z = o.z > 0.f ? o.z : 0.f;
            o.w = o.w > 0.f ? o.w : 0.f;
            if (out) *(float4*)(out + (size_t)n * 64 + fq * 4) = o;
            if (outb) {
                unsigned short t[4] = {f2bf(o.x), f2bf(o.y), f2bf(o.z), f2bf(o.w)};
                *(uint2*)(outb + (size_t)n * 64 + fq * 4) = *(uint2*)t;
            }
        }
        return;
    }

    // general path (deg > 64)
    const int end = start + deg;
    float m = -1e30f;
    for (int i = start + lane; i < end; i += 64) {
        float v = a_s[srcs[i]] + adn;
        v = (v >= 0.f) ? v : NEG_SLOPE * v;
        m = fmaxf(m, v);
    }
    m = wave_reduce_max(m);
    float l = 0.f;
    for (int i = start + lane; i < end; i += 64) {
        float v = a_s[srcs[i]] + adn;
        v = (v >= 0.f) ? v : NEG_SLOPE * v;
        l += __expf(v - m);
    }
    l = wave_reduce_sum(l);
    const float inv_den = 1.f / l;
    float acc = 0.f;
    for (int c = start; c < end; c += 64) {
        int cl = end - c;
        if (cl > 64) cl = 64;
        int sl = 0;
        float wl = 0.f;
        if (c + lane < end) {
            sl = srcs[c + lane];
            float v = a_s[sl] + adn;
            v = (v >= 0.f) ? v : NEG_SLOPE * v;
            wl = __expf(v - m) * inv_den;
        }
        for (int j = 0; j < cl; ++j) {
            float wj = __shfl(wl, j, 64);
            int sj = __shfl(sl, j, 64);
            acc += wj * h[(size_t)sj * 64 + lane];
        }
    }
    float o = acc + bias[lane];
    o = o > 0.f ? o : 0.f;
    if (out) out[(size_t)n * 64 + lane] = o;
    if (outb) outb[(size_t)n * 64 + lane] = f2bf(o);
}

// ---- fused mean-pool + final linear: one block (4 waves) per graph ----
__global__ __launch_bounds__(256) void pool_final(const float* __restrict__ x,
                                                  const int* __restrict__ gstart,
                                                  const float* __restrict__ Wlin,
                                                  const float* __restrict__ blin,
                                                  float* __restrict__ out) {
    __shared__ float red[4][64];
    const int g = blockIdx.x;
    const int lane = threadIdx.x & 63, w = threadIdx.x >> 6;
    const int s = gstart[g], e = gstart[g + 1];
    float acc = 0.f;
    for (int n = s + w; n < e; n += 4) acc += x[(size_t)n * 64 + lane];
    red[w][lane] = acc;
    __syncthreads();
    if (w == 0) {
        float p = red[0][lane] + red[1][lane] + red[2][lane] + red[3][lane];
        int c = e - s;
        p /= (float)(c > 1 ? c : 1);
        float o0 = wave_reduce_sum(p * Wlin[lane * 2 + 0]);
        float o1 = wave_reduce_sum(p * Wlin[lane * 2 + 1]);
        if (lane == 0) {
            out[g * 2 + 0] = o0 + blin[0];
            out[g * 2 + 1] = o1 + blin[1];
        }
    }
}

extern "C" void kernel_launch(void* const* d_in, const int* in_sizes, int n_in,
                              void* d_out, int out_size, void* d_ws, size_t ws_size,
                              hipStream_t stream) {
    const float* x    = (const float*)d_in[0];
    const int*   ei   = (const int*)d_in[1];
    const int*   batch= (const int*)d_in[2];
    const float* W1   = (const float*)d_in[3];
    const float* as1  = (const float*)d_in[4];
    const float* ad1  = (const float*)d_in[5];
    const float* b1   = (const float*)d_in[6];
    const float* W2   = (const float*)d_in[7];
    const float* as2  = (const float*)d_in[8];
    const float* ad2  = (const float*)d_in[9];
    const float* b2   = (const float*)d_in[10];
    const float* Wlin = (const float*)d_in[11];
    const float* blin = (const float*)d_in[12];
    float* out = (float*)d_out;

    const int FIN = 768;
    const int N  = in_sizes[0] / FIN;   // 50000
    const int E  = in_sizes[1] / 2;     // 800000
    const int ET = E + N;
    const size_t N64 = (size_t)N * 64;
    const int NB = 64;                  // scan blocks
    const int CH = (N + NB - 1) / NB;

    float* ws     = (float*)d_ws;
    float* hbuf   = ws;                          // N*64 f32 (h1, then h2)
    float* x2     = hbuf + N64;                  // N*64 f32 (layer-2 output)
    float* a_s    = x2 + N64;                    // N
    float* a_d    = a_s + N;                     // N
    int* counts   = (int*)(a_d + N);             // N (zeroed)
    int* row_ptr  = counts + N;                  // N+1
    int* next     = row_ptr + N + 1;             // N
    int* blk_sum  = next + N;                    // 64
    int* gstart   = blk_sum + 64;                // NGRAPHS+1
    int* srcs     = gstart + NGRAPHS + 1;        // ET
    uintptr_t wtp = (uintptr_t)(srcs + ET);
    wtp = (wtp + 15) & ~(uintptr_t)15;
    unsigned short* Wt1 = (unsigned short*)wtp;          // 64*768 bf16
    unsigned short* Wt2 = Wt1 + (size_t)64 * FIN;        // 64*64 bf16
    unsigned short* x1b = Wt2 + (size_t)64 * 64;         // N*64 bf16 (layer-1 out)

    const int nEdgeBlk  = (ET + 255) / 256;
    const int nWaveBlkN = (N + 3) / 4;
    const int nGemmBlk  = (N + 63) / 64;

    hipMemsetAsync(counts, 0, (size_t)N * sizeof(int), stream);

    // ---- setup (W converts, graph bounds) + edge histogram, one launch ----
    setup_hist<<<nEdgeBlk + 66, 256, 0, stream>>>(ei, E, ET, counts, nEdgeBlk,
                                                  W1, Wt1, FIN, W2, Wt2,
                                                  batch, gstart, N);
    // ---- row_ptr scan ----
    scan_sum<<<NB, 256, 0, stream>>>(counts, blk_sum, N, CH);
    scan_blk<<<1, 64, 0, stream>>>(blk_sum, row_ptr, N, NB);
    scan_local<<<NB, 256, 0, stream>>>(counts, blk_sum, row_ptr, next, N, CH);

    // ---- Layer-1 MFMA gemm + fused att, with CSR fill overlapped ----
    gemm1_fill<<<nGemmBlk + nEdgeBlk, 256, 0, stream>>>(
        x, Wt1, N, FIN, hbuf, as1, ad1, a_s, a_d, nGemmBlk, ei, E, ET, next, srcs);
    gat_agg_kernel<<<nWaveBlkN, 256, 0, stream>>>(row_ptr, srcs, a_s, a_d, hbuf,
                                                  b1, nullptr, x1b, N);

    // ---- Layer-2 MFMA gemm (bf16, no LDS) + fused att ----
    gemm2_mfma<<<nGemmBlk, 256, 0, stream>>>(x1b, Wt2, N, hbuf, as2, ad2, a_s, a_d);
    gat_agg_kernel<<<nWaveBlkN, 256, 0, stream>>>(row_ptr, srcs, a_s, a_d, hbuf,
                                                  b2, x2, nullptr, N);

    // ---- Pool + final linear ----
    pool_final<<<NGRAPHS, 256, 0, stream>>>(x2, gstart, Wlin, blin, out);
}